// Round 4
// baseline (330.258 us; speedup 1.0000x reference)
//
#include <hip/hip_runtime.h>
#include <hip/hip_bf16.h>

#define BATCH 262144
#define DIN 48
#define HDIM 256
#define DOUT 12
#define BM 64
#define NBLK (BATCH / BM)
#define EPSV 1e-5f

typedef __attribute__((ext_vector_type(4))) float f32x4;
typedef __attribute__((ext_vector_type(8))) short bf16x8;

// ws layout in ushort elements
#define W1T_OFF 0          // [256][64]   (K padded 48->64 with zeros)
#define W2T_OFF 16384      // [256][256]
#define W3T_OFF 81920      // [256][256]
#define WMT_OFF 147456     // [16][256]   (N padded 12->16 with zeros)
#define WS_ELEMS 151552

__device__ __forceinline__ unsigned short f2b(float f) {
    union { float f; unsigned u; } v; v.f = f;
    unsigned r = (v.u + 0x7fffu + ((v.u >> 16) & 1u)) >> 16;  // RNE
    return (unsigned short)r;
}

__global__ void conv_w_kernel(const float* __restrict__ W1, const float* __restrict__ W2,
                              const float* __restrict__ W3, const float* __restrict__ Wm,
                              unsigned short* __restrict__ ws) {
    int i = blockIdx.x * 256 + threadIdx.x;
    if (i >= WS_ELEMS) return;
    float v;
    if (i < W2T_OFF) {                 // W1^T [n<256][k<64]
        int n = i >> 6, k = i & 63;
        v = (k < DIN) ? W1[k * HDIM + n] : 0.0f;
    } else if (i < W3T_OFF) {          // W2^T [n][k]
        int j = i - W2T_OFF; int n = j >> 8, k = j & 255;
        v = W2[k * HDIM + n];
    } else if (i < WMT_OFF) {          // W3^T [n][k]
        int j = i - W3T_OFF; int n = j >> 8, k = j & 255;
        v = W3[k * HDIM + n];
    } else {                           // Wm^T [n<16][k<256]
        int j = i - WMT_OFF; int n = j >> 8, k = j & 255;
        v = (n < DOUT) ? Wm[k * DOUT + n] : 0.0f;
    }
    ws[i] = f2b(v);
}

// LDS swizzle: ushort index XOR ((row&7)<<3) == byte XOR ((row&7)<<4).
// Preserves 8B/16B contiguity (bits 0..2 untouched).
__device__ __forceinline__ int swz(int row, int col) {
    return row * 256 + (col ^ ((row & 7) << 3));
}

// One Linear(K->256)+LN+ReLU. buf: [64][256] bf16 swizzled, in-place.
// 8 waves: (wr=wv>>2, wc=wv&3) owns rows [wr*32,+32), cols [wc*64,+64).
// Per-lane acc = 2x4 fragments = 32 f32 -> no spill at the 128-reg cap.
template<int K>
__device__ __forceinline__ void layer_mm(
    const unsigned short* __restrict__ wt,   // W^T bf16 [256][K]
    const float* __restrict__ bias, const float* __restrict__ gg, const float* __restrict__ bb,
    unsigned short* buf, float (*red)[BM][2], float (*murs)[2])
{
    const int tid = threadIdx.x;
    const int wv = tid >> 6, lane = tid & 63, l15 = lane & 15, l4 = lane >> 4;
    const int wr = wv >> 2, wc = wv & 3;
    const int n0 = wc * 64, r0 = wr * 32;

    f32x4 acc[2][4];
    #pragma unroll
    for (int n = 0; n < 4; n++) {
        const float bv = bias[n0 + n * 16 + l15];   // fold bias into acc init
        #pragma unroll
        for (int m = 0; m < 2; m++)
            acc[m][n] = (f32x4){bv, bv, bv, bv};
    }

    #pragma unroll 2
    for (int kk = 0; kk < K; kk += 32) {
        const int k0 = kk + l4 * 8;
        bf16x8 b[4], a[2];
        #pragma unroll
        for (int n = 0; n < 4; n++)
            b[n] = *(const bf16x8*)&wt[(n0 + n * 16 + l15) * K + k0];
        #pragma unroll
        for (int m = 0; m < 2; m++)
            a[m] = *(const bf16x8*)&buf[swz(r0 + m * 16 + l15, k0)];
        #pragma unroll
        for (int m = 0; m < 2; m++)
            #pragma unroll
            for (int n = 0; n < 4; n++)
                acc[m][n] = __builtin_amdgcn_mfma_f32_16x16x32_bf16(a[m], b[n], acc[m][n], 0, 0, 0);
    }

    // per-row (sum,sumsq) over this wave's 64 cols; intra-thread 4 + 4 shfl levels
    #pragma unroll
    for (int m = 0; m < 2; m++) {
        #pragma unroll
        for (int j = 0; j < 4; j++) {
            float ss = 0.f, qq = 0.f;
            #pragma unroll
            for (int n = 0; n < 4; n++) {
                const float v = acc[m][n][j];
                ss += v; qq = fmaf(v, v, qq);
            }
            ss += __shfl_xor(ss, 1); qq += __shfl_xor(qq, 1);
            ss += __shfl_xor(ss, 2); qq += __shfl_xor(qq, 2);
            ss += __shfl_xor(ss, 4); qq += __shfl_xor(qq, 4);
            ss += __shfl_xor(ss, 8); qq += __shfl_xor(qq, 8);
            if (l15 == 0) {
                float2* p = (float2*)&red[wc][r0 + m * 16 + l4 * 4 + j][0];
                *p = make_float2(ss, qq);
            }
        }
    }
    __syncthreads();   // also drains all k-loop reads of buf

    if (tid < BM) {
        float S = 0.f, Q = 0.f;
        #pragma unroll
        for (int w = 0; w < 4; w++) { S += red[w][tid][0]; Q += red[w][tid][1]; }
        const float mu = S * (1.0f / 256.0f);
        const float var = Q * (1.0f / 256.0f) - mu * mu;
        murs[tid][0] = mu;
        murs[tid][1] = rsqrtf(var + EPSV);
    }
    __syncthreads();

    float g[4], be[4];
    #pragma unroll
    for (int n = 0; n < 4; n++) { g[n] = gg[n0 + n * 16 + l15]; be[n] = bb[n0 + n * 16 + l15]; }

    #pragma unroll
    for (int m = 0; m < 2; m++) {
        #pragma unroll
        for (int j = 0; j < 4; j++) {
            const int row = r0 + m * 16 + l4 * 4 + j;
            const float mu = murs[row][0], rs = murs[row][1];  // broadcast reads
            #pragma unroll
            for (int n = 0; n < 4; n++) {
                const float h = fmaxf(fmaf((acc[m][n][j] - mu) * rs, g[n], be[n]), 0.0f);
                buf[swz(row, n0 + n * 16 + l15)] = f2b(h);  // in-place: safe post-barrier
            }
        }
    }
    __syncthreads();
}

__global__ __launch_bounds__(512, 4) void fused_mlp(
    const float* __restrict__ x,
    const float* __restrict__ b1, const float* __restrict__ g1, const float* __restrict__ be1,
    const float* __restrict__ b2, const float* __restrict__ g2, const float* __restrict__ be2,
    const float* __restrict__ b3, const float* __restrict__ g3, const float* __restrict__ be3,
    const float* __restrict__ bm,
    const unsigned short* __restrict__ ws,
    float* __restrict__ out)
{
    __shared__ __align__(16) unsigned short buf[BM * 256];   // 32 KB, swizzled bf16
    __shared__ float red[4][BM][2];                          // 2 KB
    __shared__ float murs[BM][2];                            // 0.5 KB -> 34.5 KB total

    const int tid = threadIdx.x;
    const int wv = tid >> 6, lane = tid & 63, l15 = lane & 15, l4 = lane >> 4;
    const int wr = wv >> 2, wc = wv & 3;
    const size_t row0 = (size_t)blockIdx.x * BM;

    // ---- stage x tile -> buf as bf16 (coalesced float4 reads), pad K 48->64 ----
    {
        const float4* xs = (const float4*)(x + row0 * DIN);
        {
            const float4 f = xs[tid];                 // 0..511
            const int flat = tid * 4;
            const int r = flat / 48, c = flat % 48;
            ushort4 u = { f2b(f.x), f2b(f.y), f2b(f.z), f2b(f.w) };
            *(ushort4*)&buf[swz(r, c)] = u;
        }
        if (tid < 256) {
            const float4 f = xs[512 + tid];           // 512..767
            const int flat = (512 + tid) * 4;
            const int r = flat / 48, c = flat % 48;
            ushort4 u = { f2b(f.x), f2b(f.y), f2b(f.z), f2b(f.w) };
            *(ushort4*)&buf[swz(r, c)] = u;
        } else {
            const int t = tid - 256;                  // zero cols 48..63
            const int r = t >> 2, c = DIN + (t & 3) * 4;
            ushort4 z4 = {0, 0, 0, 0};
            *(ushort4*)&buf[swz(r, c)] = z4;
            *(ushort4*)&buf[swz(r + 32, c)] = z4;
        }
    }
    __syncthreads();

    layer_mm<64>(ws + W1T_OFF, b1, g1, be1, buf, red, murs);
    layer_mm<256>(ws + W2T_OFF, b2, g2, be2, buf, red, murs);
    layer_mm<256>(ws + W3T_OFF, b3, g3, be3, buf, red, murs);

    // ---- final layer: wave (wr,wc) = rows wr*32, k-quarter wc*64; LDS reduce ----
    {
        const unsigned short* wmt = ws + WMT_OFF;
        f32x4 facc[2] = {};
        #pragma unroll
        for (int t = 0; t < 2; t++) {
            const int k0 = wc * 64 + t * 32 + l4 * 8;
            const bf16x8 b = *(const bf16x8*)&wmt[l15 * 256 + k0];
            #pragma unroll
            for (int m = 0; m < 2; m++) {
                const bf16x8 a = *(const bf16x8*)&buf[swz(wr * 32 + m * 16 + l15, k0)];
                facc[m] = __builtin_amdgcn_mfma_f32_16x16x32_bf16(a, b, facc[m], 0, 0, 0);
            }
        }
        __syncthreads();   // all reads of buf complete before overwrite

        float* part = (float*)buf;            // [4 kq][64 rows][16 cols] = 16 KB
        #pragma unroll
        for (int m = 0; m < 2; m++)
            #pragma unroll
            for (int j = 0; j < 4; j++)
                part[(wc * 64 + wr * 32 + m * 16 + l4 * 4 + j) * 16 + l15] = facc[m][j];
        __syncthreads();

        float* ost = (float*)buf + 4096;      // [64][12] f32 at 16 KB offset
        #pragma unroll
        for (int q = 0; q < 2; q++) {
            const int cell = tid + q * 512;    // < 1024
            const int row = cell >> 4, col = cell & 15;
            float s = 0.f;
            #pragma unroll
            for (int w = 0; w < 4; w++) s += part[(w * 64 + row) * 16 + col];
            if (col < DOUT) ost[row * DOUT + col] = tanhf(s + bm[col]);
        }
        __syncthreads();

        float4* og = (float4*)(out + row0 * DOUT);
        const float4* osv = (const float4*)ost;
        if (tid < 192) og[tid] = osv[tid];     // 3 KB coalesced, full lines
    }
}

extern "C" void kernel_launch(void* const* d_in, const int* in_sizes, int n_in,
                              void* d_out, int out_size, void* d_ws, size_t ws_size,
                              hipStream_t stream)
{
    const float* x   = (const float*)d_in[0];
    const float* W1  = (const float*)d_in[1];
    const float* b1  = (const float*)d_in[2];
    const float* g1  = (const float*)d_in[3];
    const float* be1 = (const float*)d_in[4];
    const float* W2  = (const float*)d_in[5];
    const float* b2  = (const float*)d_in[6];
    const float* g2  = (const float*)d_in[7];
    const float* be2 = (const float*)d_in[8];
    const float* W3  = (const float*)d_in[9];
    const float* b3  = (const float*)d_in[10];
    const float* g3  = (const float*)d_in[11];
    const float* be3 = (const float*)d_in[12];
    const float* Wm  = (const float*)d_in[13];
    const float* bm  = (const float*)d_in[14];
    unsigned short* ws = (unsigned short*)d_ws;
    float* out = (float*)d_out;

    conv_w_kernel<<<(WS_ELEMS + 255) / 256, 256, 0, stream>>>(W1, W2, W3, Wm, ws);
    fused_mlp<<<NBLK, 512, 0, stream>>>(x, b1, g1, be1, b2, g2, be2,
                                        b3, g3, be3, bm, ws, out);
}

// Round 5
// 235.904 us; speedup vs baseline: 1.4000x; 1.4000x over previous
//
#include <hip/hip_runtime.h>
#include <hip/hip_bf16.h>

#define BATCH 262144
#define DIN 48
#define HDIM 256
#define DOUT 12
#define EPSV 1e-5f

// 256 threads (4 waves) per block; each wave owns 64 batch rows (4 r-tiles of 16).
// Activations kept TRANSPOSED in registers: C/D of mfma_16x16x32_bf16 has
// col = lane&15 = batch row, row = 4*(lane>>4) + reg = feature (verified layout).
#define ROWS_PER_BLOCK 256
#define NBLK (BATCH / ROWS_PER_BLOCK)

typedef __attribute__((ext_vector_type(4))) float f32x4;
typedef __attribute__((ext_vector_type(8))) short bf16x8;

union FragU { bf16x8 v; unsigned u[4]; };

// ws layout in ushort elements
#define W1T_OFF 0          // [256 n][64 k]  k<48: W1[k][n], k==48: b1[n], else 0
#define W2T_OFF 16384      // [256 n][256 k]
#define W3T_OFF 81920      // [256 n][256 k]
#define WMT_OFF 147456     // [16 n][256 k]  (n<12 real, else 0)
#define WS_ELEMS 151552

__device__ __forceinline__ unsigned short f2b(float f) {
    union { float f; unsigned u; } v; v.f = f;
    unsigned r = (v.u + 0x7fffu + ((v.u >> 16) & 1u)) >> 16;  // RNE
    return (unsigned short)r;
}

__device__ __forceinline__ unsigned packbf(float a, float b) {
    float2 t; t.x = a; t.y = b;
    __hip_bfloat162 h = __float22bfloat162_rn(t);   // {bf16(a)=lo, bf16(b)=hi}, RNE
    union { __hip_bfloat162 h; unsigned u; } c; c.h = h;
    return c.u;
}

__global__ void conv_w_kernel(const float* __restrict__ W1, const float* __restrict__ b1,
                              const float* __restrict__ W2, const float* __restrict__ W3,
                              const float* __restrict__ Wm,
                              unsigned short* __restrict__ ws) {
    int i = blockIdx.x * 256 + threadIdx.x;
    if (i >= WS_ELEMS) return;
    float v;
    if (i < W2T_OFF) {                 // W1^T [n][64], bias row at k=48
        int n = i >> 6, k = i & 63;
        v = (k < DIN) ? W1[k * HDIM + n] : (k == DIN ? b1[n] : 0.0f);
    } else if (i < W3T_OFF) {          // W2^T [n][k]
        int j = i - W2T_OFF; int n = j >> 8, k = j & 255;
        v = W2[k * HDIM + n];
    } else if (i < WMT_OFF) {          // W3^T [n][k]
        int j = i - W3T_OFF; int n = j >> 8, k = j & 255;
        v = W3[k * HDIM + n];
    } else {                           // Wm^T [16][256]
        int j = i - WMT_OFF; int n = j >> 8, k = j & 255;
        v = (n < DOUT) ? Wm[k * DOUT + n] : 0.0f;
    }
    ws[i] = f2b(v);
}

// K-loop over 32-wide k-slabs staged in LDS (reg-staged double buffer, 1 barrier/slab).
// slab LDS layout: [256 n][32 k] bf16 linear. A-frag (weights): row n = 16t + l15,
// k = 8q + j  -> one ds_read_b128 per (t); reused by all 4 r-tiles.
template<int KS, int KNEXT>
__device__ __forceinline__ void mm_layer(
    f32x4 (&acc)[4][16], const FragU (&bf)[4][KS],
    unsigned short (&slab)[2][8192], int& p,
    const unsigned short* __restrict__ wt, const unsigned short* __restrict__ wtnext,
    int tid, int l15, int q)
{
    #pragma unroll
    for (int s = 0; s < KS; s++) {
        int4 R0, R1, R2, R3;
        const bool pf = (s + 1 < KS) || (wtnext != nullptr);
        if (s + 1 < KS) {
            const int4* g = (const int4*)(wt + tid * (KS * 32) + (s + 1) * 32);
            R0 = g[0]; R1 = g[1]; R2 = g[2]; R3 = g[3];
        } else if (wtnext != nullptr) {
            const int4* g = (const int4*)(wtnext + tid * (KNEXT * 32));
            R0 = g[0]; R1 = g[1]; R2 = g[2]; R3 = g[3];
        }
        #pragma unroll
        for (int t = 0; t < 16; t++) {
            const bf16x8 A = *(const bf16x8*)&slab[p][(16 * t + l15) * 32 + q * 8];
            #pragma unroll
            for (int rt = 0; rt < 4; rt++)
                acc[rt][t] = __builtin_amdgcn_mfma_f32_16x16x32_bf16(A, bf[rt][s].v, acc[rt][t], 0, 0, 0);
        }
        if (pf) {
            int4* d = (int4*)&slab[p ^ 1][tid * 32];
            d[0] = R0; d[1] = R1; d[2] = R2; d[3] = R3;
        }
        __syncthreads();
        p ^= 1;
    }
}

// bias (optional) + LayerNorm + ReLU + bf16 pack + lane-group exchange into
// B-frags for the next layer (B layout: col r = l15, k = 8q + j).
__device__ __forceinline__ void build_frags(
    f32x4 (&acc)[4][16], FragU (&bfo)[4][8],
    const float2* __restrict__ gbeL, const float* __restrict__ btabL, int lane)
{
    const int l15 = lane & 15, q = lane >> 4;
    const int s1 = l15 + ((q & 1) << 5);   // source lane group 2*(q&1)
    const int s2 = s1 + 16;                // source lane group 2*(q&1)+1
    const bool lo = (q < 2);
    #pragma unroll
    for (int rt = 0; rt < 4; rt++) {
        float ss = 0.f, qq = 0.f;
        #pragma unroll
        for (int t = 0; t < 16; t++) {
            if (btabL != nullptr) {
                const float4 bt = *(const float4*)&btabL[16 * t + 4 * q];
                acc[rt][t][0] += bt.x; acc[rt][t][1] += bt.y;
                acc[rt][t][2] += bt.z; acc[rt][t][3] += bt.w;
            }
            #pragma unroll
            for (int r = 0; r < 4; r++) {
                const float v = acc[rt][t][r];
                ss += v; qq = fmaf(v, v, qq);
            }
        }
        ss += __shfl_xor(ss, 16); ss += __shfl_xor(ss, 32);
        qq += __shfl_xor(qq, 16); qq += __shfl_xor(qq, 32);
        const float mu = ss * (1.0f / 256.0f);
        const float rs = rsqrtf(fmaxf(qq * (1.0f / 256.0f) - mu * mu, 0.0f) + EPSV);
        #pragma unroll
        for (int ks = 0; ks < 8; ks++) {
            float w0[4], w1[4];
            #pragma unroll
            for (int r = 0; r < 4; r++) {
                const float2 ga = gbeL[32 * ks + 4 * q + r];        // n = 32ks+4q+r
                const float2 gb = gbeL[32 * ks + 16 + 4 * q + r];   // n = 32ks+16+4q+r
                w0[r] = fmaxf(fmaf((acc[rt][2 * ks][r] - mu) * rs, ga.x, ga.y), 0.0f);
                w1[r] = fmaxf(fmaf((acc[rt][2 * ks + 1][r] - mu) * rs, gb.x, gb.y), 0.0f);
            }
            const unsigned PLA = packbf(w0[0], w0[1]), PLB = packbf(w0[2], w0[3]);
            const unsigned PHA = packbf(w1[0], w1[1]), PHB = packbf(w1[2], w1[3]);
            const unsigned a0 = (unsigned)__shfl((int)PLA, s1), h0 = (unsigned)__shfl((int)PHA, s1);
            const unsigned a1 = (unsigned)__shfl((int)PLB, s1), h1 = (unsigned)__shfl((int)PHB, s1);
            const unsigned a2 = (unsigned)__shfl((int)PLA, s2), h2 = (unsigned)__shfl((int)PHA, s2);
            const unsigned a3 = (unsigned)__shfl((int)PLB, s2), h3 = (unsigned)__shfl((int)PHB, s2);
            bfo[rt][ks].u[0] = lo ? a0 : h0;
            bfo[rt][ks].u[1] = lo ? a1 : h1;
            bfo[rt][ks].u[2] = lo ? a2 : h2;
            bfo[rt][ks].u[3] = lo ? a3 : h3;
        }
    }
}

__device__ __forceinline__ void zero_acc(f32x4 (&acc)[4][16]) {
    #pragma unroll
    for (int rt = 0; rt < 4; rt++)
        #pragma unroll
        for (int t = 0; t < 16; t++)
            acc[rt][t] = (f32x4){0.f, 0.f, 0.f, 0.f};
}

__global__ __launch_bounds__(256, 1) void fused_mlp(
    const float* __restrict__ x,
    const float* __restrict__ g1, const float* __restrict__ be1,
    const float* __restrict__ b2, const float* __restrict__ g2, const float* __restrict__ be2,
    const float* __restrict__ b3, const float* __restrict__ g3, const float* __restrict__ be3,
    const float* __restrict__ bm,
    const unsigned short* __restrict__ ws,
    float* __restrict__ out)
{
    __shared__ unsigned short slab[2][8192];   // 32 KB weight slabs
    __shared__ float2 gbe[3][256];             // 6 KB  {g, be} per LN layer
    __shared__ float btab[2][256];             // 2 KB  b2, b3
    __shared__ float bmt[16];
    __shared__ float ostage[4][768];           // 12 KB per-wave out staging

    const int tid = threadIdx.x;
    const int wv = tid >> 6, lane = tid & 63;
    const int l15 = lane & 15, q = lane >> 4;
    const int wrow0 = blockIdx.x * ROWS_PER_BLOCK + wv * 64;

    const unsigned short* w1t = ws + W1T_OFF;
    const unsigned short* w2t = ws + W2T_OFF;
    const unsigned short* w3t = ws + W3T_OFF;
    const unsigned short* wmt = ws + WMT_OFF;

    // ---- tables -> LDS ----
    {
        const int n = tid;
        gbe[0][n] = make_float2(g1[n], be1[n]);
        gbe[1][n] = make_float2(g2[n], be2[n]);
        gbe[2][n] = make_float2(g3[n], be3[n]);
        btab[0][n] = b2[n];
        btab[1][n] = b3[n];
        if (tid < 16) bmt[tid] = (tid < DOUT) ? bm[tid] : 0.f;
    }
    // ---- stage W1^T slab0 ----
    {
        const int4* g = (const int4*)(w1t + tid * 64);
        int4 r0 = g[0], r1 = g[1], r2 = g[2], r3 = g[3];
        int4* d = (int4*)&slab[0][tid * 32];
        d[0] = r0; d[1] = r1; d[2] = r2; d[3] = r3;
    }
    // ---- x -> layer-1 B-frags (transposed, bf16), bias as constant-1 feature ----
    FragU bf1[4][2];
    #pragma unroll
    for (int rt = 0; rt < 4; rt++) {
        const float* xr = x + (size_t)(wrow0 + rt * 16 + l15) * DIN;
        const float4 f0 = *(const float4*)(xr + q * 8);
        const float4 f1 = *(const float4*)(xr + q * 8 + 4);
        bf1[rt][0].u[0] = packbf(f0.x, f0.y); bf1[rt][0].u[1] = packbf(f0.z, f0.w);
        bf1[rt][0].u[2] = packbf(f1.x, f1.y); bf1[rt][0].u[3] = packbf(f1.z, f1.w);
        if (q < 2) {
            const float4 f2 = *(const float4*)(xr + 32 + q * 8);
            const float4 f3 = *(const float4*)(xr + 36 + q * 8);
            bf1[rt][1].u[0] = packbf(f2.x, f2.y); bf1[rt][1].u[1] = packbf(f2.z, f2.w);
            bf1[rt][1].u[2] = packbf(f3.x, f3.y); bf1[rt][1].u[3] = packbf(f3.z, f3.w);
        } else if (q == 2) {
            bf1[rt][1].u[0] = 0x00003F80u;  // k=48 -> 1.0 (bias row)
            bf1[rt][1].u[1] = 0u; bf1[rt][1].u[2] = 0u; bf1[rt][1].u[3] = 0u;
        } else {
            bf1[rt][1].u[0] = 0u; bf1[rt][1].u[1] = 0u;
            bf1[rt][1].u[2] = 0u; bf1[rt][1].u[3] = 0u;
        }
    }
    __syncthreads();

    f32x4 acc[4][16];
    int p = 0;

    zero_acc(acc);
    mm_layer<2, 8>(acc, bf1, slab, p, w1t, w2t, tid, l15, q);
    FragU bf[4][8];
    build_frags(acc, bf, &gbe[0][0], nullptr, lane);

    zero_acc(acc);
    mm_layer<8, 8>(acc, bf, slab, p, w2t, w3t, tid, l15, q);
    build_frags(acc, bf, &gbe[1][0], &btab[0][0], lane);

    zero_acc(acc);
    mm_layer<8, 8>(acc, bf, slab, p, w3t, (const unsigned short*)nullptr, tid, l15, q);
    build_frags(acc, bf, &gbe[2][0], &btab[1][0], lane);

    // ---- final layer: Wm^T from global (L2-resident, 8 KB) ----
    f32x4 facc[4];
    #pragma unroll
    for (int rt = 0; rt < 4; rt++) facc[rt] = (f32x4){0.f, 0.f, 0.f, 0.f};
    #pragma unroll
    for (int ks = 0; ks < 8; ks++) {
        const bf16x8 A = *(const bf16x8*)&wmt[l15 * 256 + ks * 32 + q * 8];
        #pragma unroll
        for (int rt = 0; rt < 4; rt++)
            facc[rt] = __builtin_amdgcn_mfma_f32_16x16x32_bf16(A, bf[rt][ks].v, facc[rt], 0, 0, 0);
    }
    // bm + tanh -> wave-private LDS staging (row = rt*16+l15, cols n = 4q..4q+3)
    if (q < 3) {
        const float4 bmv = *(const float4*)&bmt[4 * q];
        #pragma unroll
        for (int rt = 0; rt < 4; rt++) {
            float4 o;
            o.x = tanhf(facc[rt][0] + bmv.x);
            o.y = tanhf(facc[rt][1] + bmv.y);
            o.z = tanhf(facc[rt][2] + bmv.z);
            o.w = tanhf(facc[rt][3] + bmv.w);
            *(float4*)&ostage[wv][(rt * 16 + l15) * 12 + q * 4] = o;
        }
    }
    // coalesced store: 64 rows x 12 f32 = 192 float4 per wave
    float4* og = (float4*)(out + (size_t)wrow0 * DOUT);
    const float4* ov = (const float4*)&ostage[wv][0];
    #pragma unroll
    for (int i = 0; i < 3; i++) og[lane + 64 * i] = ov[lane + 64 * i];
}

extern "C" void kernel_launch(void* const* d_in, const int* in_sizes, int n_in,
                              void* d_out, int out_size, void* d_ws, size_t ws_size,
                              hipStream_t stream)
{
    const float* x   = (const float*)d_in[0];
    const float* W1  = (const float*)d_in[1];
    const float* b1  = (const float*)d_in[2];
    const float* g1  = (const float*)d_in[3];
    const float* be1 = (const float*)d_in[4];
    const float* W2  = (const float*)d_in[5];
    const float* b2  = (const float*)d_in[6];
    const float* g2  = (const float*)d_in[7];
    const float* be2 = (const float*)d_in[8];
    const float* W3  = (const float*)d_in[9];
    const float* b3  = (const float*)d_in[10];
    const float* g3  = (const float*)d_in[11];
    const float* be3 = (const float*)d_in[12];
    const float* Wm  = (const float*)d_in[13];
    const float* bm  = (const float*)d_in[14];
    unsigned short* ws = (unsigned short*)d_ws;
    float* out = (float*)d_out;

    conv_w_kernel<<<(WS_ELEMS + 255) / 256, 256, 0, stream>>>(W1, b1, W2, W3, Wm, ws);
    fused_mlp<<<NBLK, 256, 0, stream>>>(x, g1, be1, b2, g2, be2,
                                        b3, g3, be3, bm, ws, out);
}

// Round 6
// 155.932 us; speedup vs baseline: 2.1180x; 1.5129x over previous
//
#include <hip/hip_runtime.h>
#include <hip/hip_bf16.h>

#define BATCH 262144
#define DIN 48
#define HDIM 256
#define DOUT 12
#define EPSV 1e-5f

// 512 threads (8 waves) per block; each wave owns 32 batch rows (2 r-tiles of 16).
// Activations TRANSPOSED in registers: C/D of mfma_16x16x32_bf16:
// col = lane&15 = batch row, row(feature) = 4*(lane>>4) + reg.
#define ROWS_PER_BLOCK 256
#define NBLK (BATCH / ROWS_PER_BLOCK)

typedef __attribute__((ext_vector_type(4))) float f32x4;
typedef __attribute__((ext_vector_type(8))) short bf16x8;

union FragU { bf16x8 v; unsigned u[4]; };

// ws layout (ushort), FRAGMENT-MAJOR everywhere:
//   idx-in-region = ((s*16 + t)*64 + lane)*8 + j
//   encodes W^T[n = 16t + (lane&15)][k = 32s + 8*(lane>>4) + j]
// so a wave's A-frag for (slab s, tile t) is 64 consecutive 16B chunks.
#define W1F_OFF 0          // 2 slabs  (K=64: k<48 -> W1, k==48 -> b1, else 0)
#define W2F_OFF 16384      // 8 slabs
#define W3F_OFF 81920      // 8 slabs
#define WMF_OFF 147456     // 8 slabs of a single t: n = lane&15 (n<12 real)
#define WS_ELEMS 151552

__device__ __forceinline__ unsigned short f2b(float f) {
    union { float f; unsigned u; } v; v.f = f;
    unsigned r = (v.u + 0x7fffu + ((v.u >> 16) & 1u)) >> 16;  // RNE
    return (unsigned short)r;
}

__device__ __forceinline__ unsigned packbf(float a, float b) {
    float2 t; t.x = a; t.y = b;
    __hip_bfloat162 h = __float22bfloat162_rn(t);
    union { __hip_bfloat162 h; unsigned u; } c; c.h = h;
    return c.u;
}

__global__ void conv_w_kernel(const float* __restrict__ W1, const float* __restrict__ b1,
                              const float* __restrict__ W2, const float* __restrict__ W3,
                              const float* __restrict__ Wm,
                              unsigned short* __restrict__ ws) {
    int i = blockIdx.x * 256 + threadIdx.x;
    if (i >= WS_ELEMS) return;
    float v;
    if (i < W2F_OFF) {
        const int j = i & 7, l = (i >> 3) & 63, t = (i >> 9) & 15, s = i >> 13;
        const int n = 16 * t + (l & 15), k = 32 * s + 8 * (l >> 4) + j;
        v = (k < DIN) ? W1[k * HDIM + n] : (k == DIN ? b1[n] : 0.0f);
    } else if (i < W3F_OFF) {
        const int i2 = i - W2F_OFF;
        const int j = i2 & 7, l = (i2 >> 3) & 63, t = (i2 >> 9) & 15, s = i2 >> 13;
        const int n = 16 * t + (l & 15), k = 32 * s + 8 * (l >> 4) + j;
        v = W2[k * HDIM + n];
    } else if (i < WMF_OFF) {
        const int i3 = i - W3F_OFF;
        const int j = i3 & 7, l = (i3 >> 3) & 63, t = (i3 >> 9) & 15, s = i3 >> 13;
        const int n = 16 * t + (l & 15), k = 32 * s + 8 * (l >> 4) + j;
        v = W3[k * HDIM + n];
    } else {
        const int i4 = i - WMF_OFF;
        const int j = i4 & 7, l = (i4 >> 3) & 63, ks = i4 >> 9;
        const int n = l & 15, k = 32 * ks + 8 * (l >> 4) + j;
        v = (n < DOUT) ? Wm[k * DOUT + n] : 0.0f;
    }
    ws[i] = f2b(v);
}

// K-loop over 32-wide k-slabs staged in LDS (reg-staged double buffer,
// 1 barrier/slab). slab is fragment-major: A-frag(t) = slab + t*1024B + lane*16B
// -> conflict-free linear ds_read_b128, immediate offsets per t.
template<int KS, int KNEXT>
__device__ __forceinline__ void mm_layer(
    f32x4 (&acc)[2][16], const FragU (&bf)[2][KS],
    unsigned short (&slab)[2][8192], int& p,
    const unsigned short* __restrict__ wt, const unsigned short* __restrict__ wtnext,
    int tid, int lane)
{
    #pragma unroll
    for (int s = 0; s < KS; s++) {
        int4 R0, R1;
        const bool pf = (s + 1 < KS) || (wtnext != nullptr);
        if (s + 1 < KS) {
            const int4* g = (const int4*)(wt + (s + 1) * 8192 + tid * 16);
            R0 = g[0]; R1 = g[1];
        } else if (wtnext != nullptr) {
            const int4* g = (const int4*)(wtnext + tid * 16);
            R0 = g[0]; R1 = g[1];
        }
        #pragma unroll
        for (int t = 0; t < 16; t++) {
            const bf16x8 A = *(const bf16x8*)&slab[p][(t * 64 + lane) * 8];
            acc[0][t] = __builtin_amdgcn_mfma_f32_16x16x32_bf16(A, bf[0][s].v, acc[0][t], 0, 0, 0);
            acc[1][t] = __builtin_amdgcn_mfma_f32_16x16x32_bf16(A, bf[1][s].v, acc[1][t], 0, 0, 0);
        }
        if (pf) {
            int4* d = (int4*)&slab[p ^ 1][tid * 16];
            d[0] = R0; d[1] = R1;
        }
        __syncthreads();
        p ^= 1;
    }
}

// bias (optional) + LayerNorm + ReLU + bf16 pack + lane-group exchange into
// next-layer B-frags (B layout: col = l15, k = 8q + j).
__device__ __forceinline__ void build_frags(
    f32x4 (&acc)[2][16], FragU (&bfo)[2][8],
    const float2* __restrict__ gbeL, const float* __restrict__ btabL, int lane)
{
    const int l15 = lane & 15, q = lane >> 4;
    const int s1 = l15 + ((q & 1) << 5);
    const int s2 = s1 + 16;
    const bool lo = (q < 2);
    #pragma unroll
    for (int rt = 0; rt < 2; rt++) {
        float ss = 0.f, qq = 0.f;
        #pragma unroll
        for (int t = 0; t < 16; t++) {
            if (btabL != nullptr) {
                const float4 bt = *(const float4*)&btabL[16 * t + 4 * q];
                acc[rt][t][0] += bt.x; acc[rt][t][1] += bt.y;
                acc[rt][t][2] += bt.z; acc[rt][t][3] += bt.w;
            }
            #pragma unroll
            for (int r = 0; r < 4; r++) {
                const float v = acc[rt][t][r];
                ss += v; qq = fmaf(v, v, qq);
            }
        }
        ss += __shfl_xor(ss, 16); ss += __shfl_xor(ss, 32);
        qq += __shfl_xor(qq, 16); qq += __shfl_xor(qq, 32);
        const float mu = ss * (1.0f / 256.0f);
        const float rs = rsqrtf(fmaxf(qq * (1.0f / 256.0f) - mu * mu, 0.0f) + EPSV);
        #pragma unroll
        for (int ks = 0; ks < 8; ks++) {
            float w0[4], w1[4];
            #pragma unroll
            for (int r = 0; r < 4; r++) {
                const float2 ga = gbeL[32 * ks + 4 * q + r];
                const float2 gb = gbeL[32 * ks + 16 + 4 * q + r];
                w0[r] = fmaxf(fmaf((acc[rt][2 * ks][r] - mu) * rs, ga.x, ga.y), 0.0f);
                w1[r] = fmaxf(fmaf((acc[rt][2 * ks + 1][r] - mu) * rs, gb.x, gb.y), 0.0f);
            }
            const unsigned PLA = packbf(w0[0], w0[1]), PLB = packbf(w0[2], w0[3]);
            const unsigned PHA = packbf(w1[0], w1[1]), PHB = packbf(w1[2], w1[3]);
            const unsigned a0 = (unsigned)__shfl((int)PLA, s1), h0 = (unsigned)__shfl((int)PHA, s1);
            const unsigned a1 = (unsigned)__shfl((int)PLB, s1), h1 = (unsigned)__shfl((int)PHB, s1);
            const unsigned a2 = (unsigned)__shfl((int)PLA, s2), h2 = (unsigned)__shfl((int)PHA, s2);
            const unsigned a3 = (unsigned)__shfl((int)PLB, s2), h3 = (unsigned)__shfl((int)PHB, s2);
            bfo[rt][ks].u[0] = lo ? a0 : h0;
            bfo[rt][ks].u[1] = lo ? a1 : h1;
            bfo[rt][ks].u[2] = lo ? a2 : h2;
            bfo[rt][ks].u[3] = lo ? a3 : h3;
        }
    }
}

__device__ __forceinline__ void zero_acc(f32x4 (&acc)[2][16]) {
    #pragma unroll
    for (int rt = 0; rt < 2; rt++)
        #pragma unroll
        for (int t = 0; t < 16; t++)
            acc[rt][t] = (f32x4){0.f, 0.f, 0.f, 0.f};
}

__global__ __launch_bounds__(512, 2) void fused_mlp(
    const float* __restrict__ x,
    const float* __restrict__ g1, const float* __restrict__ be1,
    const float* __restrict__ b2, const float* __restrict__ g2, const float* __restrict__ be2,
    const float* __restrict__ b3, const float* __restrict__ g3, const float* __restrict__ be3,
    const float* __restrict__ bm,
    const unsigned short* __restrict__ ws,
    float* __restrict__ out)
{
    __shared__ unsigned short slab[2][8192];   // 32 KB weight slabs (frag-major)
    __shared__ float2 gbe[3][256];             // 6 KB
    __shared__ float btab[2][256];             // 2 KB
    __shared__ float bmt[16];
    __shared__ float ostage[8][384];           // 12 KB per-wave out staging

    const int tid = threadIdx.x;
    const int wv = tid >> 6, lane = tid & 63;
    const int l15 = lane & 15, q = lane >> 4;
    const int wrow0 = blockIdx.x * ROWS_PER_BLOCK + wv * 32;

    const unsigned short* w1f = ws + W1F_OFF;
    const unsigned short* w2f = ws + W2F_OFF;
    const unsigned short* w3f = ws + W3F_OFF;
    const unsigned short* wmf = ws + WMF_OFF;

    // ---- tables -> LDS ----
    if (tid < 256) {
        const int n = tid;
        gbe[0][n] = make_float2(g1[n], be1[n]);
        gbe[1][n] = make_float2(g2[n], be2[n]);
        gbe[2][n] = make_float2(g3[n], be3[n]);
        btab[0][n] = b2[n];
        btab[1][n] = b3[n];
        if (tid < 16) bmt[tid] = (tid < DOUT) ? bm[tid] : 0.f;
    }
    // ---- stage W1 slab0 (frag-major identity copy) ----
    {
        const int4* g = (const int4*)(w1f + tid * 16);
        int4 r0 = g[0], r1 = g[1];
        int4* d = (int4*)&slab[0][tid * 16];
        d[0] = r0; d[1] = r1;
    }
    // ---- x -> layer-1 B-frags (transposed bf16), bias as constant-1 feature ----
    FragU bf1[2][2];
    #pragma unroll
    for (int rt = 0; rt < 2; rt++) {
        const float* xr = x + (size_t)(wrow0 + rt * 16 + l15) * DIN;
        const float4 f0 = *(const float4*)(xr + q * 8);
        const float4 f1 = *(const float4*)(xr + q * 8 + 4);
        bf1[rt][0].u[0] = packbf(f0.x, f0.y); bf1[rt][0].u[1] = packbf(f0.z, f0.w);
        bf1[rt][0].u[2] = packbf(f1.x, f1.y); bf1[rt][0].u[3] = packbf(f1.z, f1.w);
        if (q < 2) {
            const float4 f2 = *(const float4*)(xr + 32 + q * 8);
            const float4 f3 = *(const float4*)(xr + 36 + q * 8);
            bf1[rt][1].u[0] = packbf(f2.x, f2.y); bf1[rt][1].u[1] = packbf(f2.z, f2.w);
            bf1[rt][1].u[2] = packbf(f3.x, f3.y); bf1[rt][1].u[3] = packbf(f3.z, f3.w);
        } else if (q == 2) {
            bf1[rt][1].u[0] = 0x00003F80u;  // k=48 -> 1.0 (bias row)
            bf1[rt][1].u[1] = 0u; bf1[rt][1].u[2] = 0u; bf1[rt][1].u[3] = 0u;
        } else {
            bf1[rt][1].u[0] = 0u; bf1[rt][1].u[1] = 0u;
            bf1[rt][1].u[2] = 0u; bf1[rt][1].u[3] = 0u;
        }
    }
    __syncthreads();

    f32x4 acc[2][16];
    int p = 0;

    zero_acc(acc);
    mm_layer<2, 8>(acc, bf1, slab, p, w1f, w2f, tid, lane);
    FragU bf[2][8];
    build_frags(acc, bf, &gbe[0][0], nullptr, lane);

    zero_acc(acc);
    mm_layer<8, 8>(acc, bf, slab, p, w2f, w3f, tid, lane);
    build_frags(acc, bf, &gbe[1][0], &btab[0][0], lane);

    zero_acc(acc);
    mm_layer<8, 8>(acc, bf, slab, p, w3f, (const unsigned short*)nullptr, tid, lane);
    build_frags(acc, bf, &gbe[2][0], &btab[1][0], lane);

    // ---- final layer: Wm frag-major from global (L2-resident, 8 KB) ----
    f32x4 facc[2] = {{0.f, 0.f, 0.f, 0.f}, {0.f, 0.f, 0.f, 0.f}};
    #pragma unroll
    for (int ks = 0; ks < 8; ks++) {
        const bf16x8 A = *(const bf16x8*)&wmf[(ks * 64 + lane) * 8];
        facc[0] = __builtin_amdgcn_mfma_f32_16x16x32_bf16(A, bf[0][ks].v, facc[0], 0, 0, 0);
        facc[1] = __builtin_amdgcn_mfma_f32_16x16x32_bf16(A, bf[1][ks].v, facc[1], 0, 0, 0);
    }
    // bm + tanh -> wave-private LDS staging (row = rt*16+l15, cols 4q..4q+3)
    if (q < 3) {
        const float4 bmv = *(const float4*)&bmt[4 * q];
        #pragma unroll
        for (int rt = 0; rt < 2; rt++) {
            float4 o;
            o.x = tanhf(facc[rt][0] + bmv.x);
            o.y = tanhf(facc[rt][1] + bmv.y);
            o.z = tanhf(facc[rt][2] + bmv.z);
            o.w = tanhf(facc[rt][3] + bmv.w);
            *(float4*)&ostage[wv][(rt * 16 + l15) * 12 + q * 4] = o;
        }
    }
    // coalesced store: 32 rows x 12 f32 = 96 float4 per wave
    float4* og = (float4*)(out + (size_t)wrow0 * DOUT);
    const float4* ov = (const float4*)&ostage[wv][0];
    og[lane] = ov[lane];
    if (lane < 32) og[64 + lane] = ov[64 + lane];
}

extern "C" void kernel_launch(void* const* d_in, const int* in_sizes, int n_in,
                              void* d_out, int out_size, void* d_ws, size_t ws_size,
                              hipStream_t stream)
{
    const float* x   = (const float*)d_in[0];
    const float* W1  = (const float*)d_in[1];
    const float* b1  = (const float*)d_in[2];
    const float* g1  = (const float*)d_in[3];
    const float* be1 = (const float*)d_in[4];
    const float* W2  = (const float*)d_in[5];
    const float* b2  = (const float*)d_in[6];
    const float* g2  = (const float*)d_in[7];
    const float* be2 = (const float*)d_in[8];
    const float* W3  = (const float*)d_in[9];
    const float* b3  = (const float*)d_in[10];
    const float* g3  = (const float*)d_in[11];
    const float* be3 = (const float*)d_in[12];
    const float* Wm  = (const float*)d_in[13];
    const float* bm  = (const float*)d_in[14];
    unsigned short* ws = (unsigned short*)d_ws;
    float* out = (float*)d_out;

    conv_w_kernel<<<(WS_ELEMS + 255) / 256, 256, 0, stream>>>(W1, b1, W2, W3, Wm, ws);
    fused_mlp<<<NBLK, 512, 0, stream>>>(x, g1, be1, b2, g2, be2,
                                        b3, g3, be3, bm, ws, out);
}

// Round 7
// 150.503 us; speedup vs baseline: 2.1944x; 1.0361x over previous
//
#include <hip/hip_runtime.h>
#include <hip/hip_bf16.h>

#define BATCH 262144
#define DIN 48
#define HDIM 256
#define DOUT 12
#define EPSV 1e-5f

// 512 threads (8 waves) per block; each wave owns 32 batch rows (2 r-tiles of 16).
// Activations TRANSPOSED in registers: C/D of mfma_16x16x32_bf16:
// col = lane&15 = batch row, row(feature) = 4*(lane>>4) + reg.
// Weights for layers 2/3/final use a PERMUTED k-order phi(s,q,j) =
// 32s + 16*(j>=4) + 4q + (j&3) so next-layer B-frags are lane-local
// (no cross-lane exchange needed after LN).
#define ROWS_PER_BLOCK 256
#define NBLK (BATCH / ROWS_PER_BLOCK)

typedef __attribute__((ext_vector_type(4))) float f32x4;
typedef __attribute__((ext_vector_type(8))) short bf16x8;

union FragU { bf16x8 v; unsigned u[4]; };

// ws layout (ushort), FRAGMENT-MAJOR:
//   idx-in-region = ((s*16 + t)*64 + lane)*8 + j
//   W1 region: k = 32s + 8*(lane>>4) + j          (linear; x frags built linear)
//   W2/W3/Wm:  k = phi(s, lane>>4, j)             (permuted; frags lane-local)
#define W1F_OFF 0          // 2 slabs  (K=64: k<48 -> W1, k==48 -> b1, else 0)
#define W2F_OFF 16384      // 8 slabs
#define W3F_OFF 81920      // 8 slabs
#define WMF_OFF 147456     // 8 slabs of a single t: n = lane&15 (n<12 real)
#define WS_ELEMS 151552

__device__ __forceinline__ unsigned short f2b(float f) {
    union { float f; unsigned u; } v; v.f = f;
    unsigned r = (v.u + 0x7fffu + ((v.u >> 16) & 1u)) >> 16;  // RNE
    return (unsigned short)r;
}

__device__ __forceinline__ unsigned packbf(float a, float b) {
    float2 t; t.x = a; t.y = b;
    __hip_bfloat162 h = __float22bfloat162_rn(t);
    union { __hip_bfloat162 h; unsigned u; } c; c.h = h;
    return c.u;
}

__global__ void conv_w_kernel(const float* __restrict__ W1, const float* __restrict__ b1,
                              const float* __restrict__ W2, const float* __restrict__ W3,
                              const float* __restrict__ Wm,
                              unsigned short* __restrict__ ws) {
    int i = blockIdx.x * 256 + threadIdx.x;
    if (i >= WS_ELEMS) return;
    float v;
    if (i < W2F_OFF) {
        const int j = i & 7, l = (i >> 3) & 63, t = (i >> 9) & 15, s = i >> 13;
        const int n = 16 * t + (l & 15), k = 32 * s + 8 * (l >> 4) + j;  // linear
        v = (k < DIN) ? W1[k * HDIM + n] : (k == DIN ? b1[n] : 0.0f);
    } else if (i < W3F_OFF) {
        const int i2 = i - W2F_OFF;
        const int j = i2 & 7, l = (i2 >> 3) & 63, t = (i2 >> 9) & 15, s = i2 >> 13;
        const int n = 16 * t + (l & 15);
        const int k = 32 * s + ((j >= 4) ? 16 : 0) + 4 * (l >> 4) + (j & 3);  // phi
        v = W2[k * HDIM + n];
    } else if (i < WMF_OFF) {
        const int i3 = i - W3F_OFF;
        const int j = i3 & 7, l = (i3 >> 3) & 63, t = (i3 >> 9) & 15, s = i3 >> 13;
        const int n = 16 * t + (l & 15);
        const int k = 32 * s + ((j >= 4) ? 16 : 0) + 4 * (l >> 4) + (j & 3);  // phi
        v = W3[k * HDIM + n];
    } else {
        const int i4 = i - WMF_OFF;
        const int j = i4 & 7, l = (i4 >> 3) & 63, ks = i4 >> 9;
        const int n = l & 15;
        const int k = 32 * ks + ((j >= 4) ? 16 : 0) + 4 * (l >> 4) + (j & 3); // phi
        v = (n < DOUT) ? Wm[k * DOUT + n] : 0.0f;
    }
    ws[i] = f2b(v);
}

// K-loop over 32-wide k-slabs staged in LDS (reg-staged double buffer,
// 1 barrier/slab). slab is fragment-major: A-frag(t) = slab + t*1024B + lane*16B
// -> conflict-free linear ds_read_b128, immediate offsets per t.
template<int KS, int KNEXT>
__device__ __forceinline__ void mm_layer(
    f32x4 (&acc)[2][16], const FragU (&bf)[2][KS],
    unsigned short (&slab)[2][8192], int& p,
    const unsigned short* __restrict__ wt, const unsigned short* __restrict__ wtnext,
    int tid, int lane)
{
    #pragma unroll
    for (int s = 0; s < KS; s++) {
        int4 R0, R1;
        const bool pf = (s + 1 < KS) || (wtnext != nullptr);
        if (s + 1 < KS) {
            const int4* g = (const int4*)(wt + (s + 1) * 8192 + tid * 16);
            R0 = g[0]; R1 = g[1];
        } else if (wtnext != nullptr) {
            const int4* g = (const int4*)(wtnext + tid * 16);
            R0 = g[0]; R1 = g[1];
        }
        #pragma unroll
        for (int t = 0; t < 16; t++) {
            const bf16x8 A = *(const bf16x8*)&slab[p][(t * 64 + lane) * 8];
            acc[0][t] = __builtin_amdgcn_mfma_f32_16x16x32_bf16(A, bf[0][s].v, acc[0][t], 0, 0, 0);
            acc[1][t] = __builtin_amdgcn_mfma_f32_16x16x32_bf16(A, bf[1][s].v, acc[1][t], 0, 0, 0);
        }
        if (pf) {
            int4* d = (int4*)&slab[p ^ 1][tid * 16];
            d[0] = R0; d[1] = R1;
        }
        __syncthreads();
        p ^= 1;
    }
}

// bias (optional) + LayerNorm + ReLU + bf16 pack. B-frags for the next layer
// are LANE-LOCAL thanks to the phi-permuted weight k-order:
//   u[0..1] <- features 32ks+4q+{0..3}   (t = 2ks)
//   u[2..3] <- features 32ks+16+4q+{0..3}(t = 2ks+1)
__device__ __forceinline__ void build_frags(
    f32x4 (&acc)[2][16], FragU (&bfo)[2][8],
    const float2* __restrict__ gbeL, const float* __restrict__ btabL, int lane)
{
    const int q = lane >> 4;
    #pragma unroll
    for (int rt = 0; rt < 2; rt++) {
        float ss = 0.f, qq = 0.f;
        #pragma unroll
        for (int t = 0; t < 16; t++) {
            if (btabL != nullptr) {
                const float4 bt = *(const float4*)&btabL[16 * t + 4 * q];
                acc[rt][t][0] += bt.x; acc[rt][t][1] += bt.y;
                acc[rt][t][2] += bt.z; acc[rt][t][3] += bt.w;
            }
            #pragma unroll
            for (int r = 0; r < 4; r++) {
                const float v = acc[rt][t][r];
                ss += v; qq = fmaf(v, v, qq);
            }
        }
        ss += __shfl_xor(ss, 16); ss += __shfl_xor(ss, 32);
        qq += __shfl_xor(qq, 16); qq += __shfl_xor(qq, 32);
        const float mu = ss * (1.0f / 256.0f);
        const float rs = rsqrtf(fmaxf(qq * (1.0f / 256.0f) - mu * mu, 0.0f) + EPSV);
        #pragma unroll
        for (int ks = 0; ks < 8; ks++) {
            float w0[4], w1[4];
            #pragma unroll
            for (int r = 0; r < 4; r++) {
                const float2 ga = gbeL[32 * ks + 4 * q + r];
                const float2 gb = gbeL[32 * ks + 16 + 4 * q + r];
                w0[r] = fmaxf(fmaf((acc[rt][2 * ks][r] - mu) * rs, ga.x, ga.y), 0.0f);
                w1[r] = fmaxf(fmaf((acc[rt][2 * ks + 1][r] - mu) * rs, gb.x, gb.y), 0.0f);
            }
            bfo[rt][ks].u[0] = packbf(w0[0], w0[1]);
            bfo[rt][ks].u[1] = packbf(w0[2], w0[3]);
            bfo[rt][ks].u[2] = packbf(w1[0], w1[1]);
            bfo[rt][ks].u[3] = packbf(w1[2], w1[3]);
        }
    }
}

__device__ __forceinline__ void zero_acc(f32x4 (&acc)[2][16]) {
    #pragma unroll
    for (int rt = 0; rt < 2; rt++)
        #pragma unroll
        for (int t = 0; t < 16; t++)
            acc[rt][t] = (f32x4){0.f, 0.f, 0.f, 0.f};
}

__global__ __launch_bounds__(512, 2) void fused_mlp(
    const float* __restrict__ x,
    const float* __restrict__ g1, const float* __restrict__ be1,
    const float* __restrict__ b2, const float* __restrict__ g2, const float* __restrict__ be2,
    const float* __restrict__ b3, const float* __restrict__ g3, const float* __restrict__ be3,
    const float* __restrict__ bm,
    const unsigned short* __restrict__ ws,
    float* __restrict__ out)
{
    __shared__ unsigned short slab[2][8192];   // 32 KB weight slabs (frag-major)
    __shared__ float2 gbe[3][256];             // 6 KB
    __shared__ float btab[2][256];             // 2 KB
    __shared__ float bmt[16];
    __shared__ float ostage[8][384];           // 12 KB per-wave out staging

    const int tid = threadIdx.x;
    const int wv = tid >> 6, lane = tid & 63;
    const int l15 = lane & 15, q = lane >> 4;
    const int wrow0 = blockIdx.x * ROWS_PER_BLOCK + wv * 32;

    const unsigned short* w1f = ws + W1F_OFF;
    const unsigned short* w2f = ws + W2F_OFF;
    const unsigned short* w3f = ws + W3F_OFF;
    const unsigned short* wmf = ws + WMF_OFF;

    // ---- tables -> LDS ----
    if (tid < 256) {
        const int n = tid;
        gbe[0][n] = make_float2(g1[n], be1[n]);
        gbe[1][n] = make_float2(g2[n], be2[n]);
        gbe[2][n] = make_float2(g3[n], be3[n]);
        btab[0][n] = b2[n];
        btab[1][n] = b3[n];
        if (tid < 16) bmt[tid] = (tid < DOUT) ? bm[tid] : 0.f;
    }
    // ---- stage W1 slab0 (frag-major identity copy) ----
    {
        const int4* g = (const int4*)(w1f + tid * 16);
        int4 r0 = g[0], r1 = g[1];
        int4* d = (int4*)&slab[0][tid * 16];
        d[0] = r0; d[1] = r1;
    }
    // ---- x -> layer-1 B-frags (transposed bf16), bias as constant-1 feature ----
    FragU bf1[2][2];
    #pragma unroll
    for (int rt = 0; rt < 2; rt++) {
        const float* xr = x + (size_t)(wrow0 + rt * 16 + l15) * DIN;
        const float4 f0 = *(const float4*)(xr + q * 8);
        const float4 f1 = *(const float4*)(xr + q * 8 + 4);
        bf1[rt][0].u[0] = packbf(f0.x, f0.y); bf1[rt][0].u[1] = packbf(f0.z, f0.w);
        bf1[rt][0].u[2] = packbf(f1.x, f1.y); bf1[rt][0].u[3] = packbf(f1.z, f1.w);
        if (q < 2) {
            const float4 f2 = *(const float4*)(xr + 32 + q * 8);
            const float4 f3 = *(const float4*)(xr + 36 + q * 8);
            bf1[rt][1].u[0] = packbf(f2.x, f2.y); bf1[rt][1].u[1] = packbf(f2.z, f2.w);
            bf1[rt][1].u[2] = packbf(f3.x, f3.y); bf1[rt][1].u[3] = packbf(f3.z, f3.w);
        } else if (q == 2) {
            bf1[rt][1].u[0] = 0x00003F80u;  // k=48 -> 1.0 (bias row)
            bf1[rt][1].u[1] = 0u; bf1[rt][1].u[2] = 0u; bf1[rt][1].u[3] = 0u;
        } else {
            bf1[rt][1].u[0] = 0u; bf1[rt][1].u[1] = 0u;
            bf1[rt][1].u[2] = 0u; bf1[rt][1].u[3] = 0u;
        }
    }
    __syncthreads();

    f32x4 acc[2][16];
    int p = 0;

    zero_acc(acc);
    mm_layer<2, 8>(acc, bf1, slab, p, w1f, w2f, tid, lane);
    FragU bf[2][8];
    build_frags(acc, bf, &gbe[0][0], nullptr, lane);

    zero_acc(acc);
    mm_layer<8, 8>(acc, bf, slab, p, w2f, w3f, tid, lane);
    build_frags(acc, bf, &gbe[1][0], &btab[0][0], lane);

    zero_acc(acc);
    mm_layer<8, 8>(acc, bf, slab, p, w3f, (const unsigned short*)nullptr, tid, lane);
    build_frags(acc, bf, &gbe[2][0], &btab[1][0], lane);

    // ---- final layer: Wm frag-major (phi k-order) from global (L2-resident) ----
    f32x4 facc[2] = {{0.f, 0.f, 0.f, 0.f}, {0.f, 0.f, 0.f, 0.f}};
    #pragma unroll
    for (int ks = 0; ks < 8; ks++) {
        const bf16x8 A = *(const bf16x8*)&wmf[(ks * 64 + lane) * 8];
        facc[0] = __builtin_amdgcn_mfma_f32_16x16x32_bf16(A, bf[0][ks].v, facc[0], 0, 0, 0);
        facc[1] = __builtin_amdgcn_mfma_f32_16x16x32_bf16(A, bf[1][ks].v, facc[1], 0, 0, 0);
    }
    // bm + tanh -> wave-private LDS staging (row = rt*16+l15, cols 4q..4q+3)
    if (q < 3) {
        const float4 bmv = *(const float4*)&bmt[4 * q];
        #pragma unroll
        for (int rt = 0; rt < 2; rt++) {
            float4 o;
            o.x = tanhf(facc[rt][0] + bmv.x);
            o.y = tanhf(facc[rt][1] + bmv.y);
            o.z = tanhf(facc[rt][2] + bmv.z);
            o.w = tanhf(facc[rt][3] + bmv.w);
            *(float4*)&ostage[wv][(rt * 16 + l15) * 12 + q * 4] = o;
        }
    }
    // coalesced store: 32 rows x 12 f32 = 96 float4 per wave
    float4* og = (float4*)(out + (size_t)wrow0 * DOUT);
    const float4* ov = (const float4*)&ostage[wv][0];
    og[lane] = ov[lane];
    if (lane < 32) og[64 + lane] = ov[64 + lane];
}

extern "C" void kernel_launch(void* const* d_in, const int* in_sizes, int n_in,
                              void* d_out, int out_size, void* d_ws, size_t ws_size,
                              hipStream_t stream)
{
    const float* x   = (const float*)d_in[0];
    const float* W1  = (const float*)d_in[1];
    const float* b1  = (const float*)d_in[2];
    const float* g1  = (const float*)d_in[3];
    const float* be1 = (const float*)d_in[4];
    const float* W2  = (const float*)d_in[5];
    const float* b2  = (const float*)d_in[6];
    const float* g2  = (const float*)d_in[7];
    const float* be2 = (const float*)d_in[8];
    const float* W3  = (const float*)d_in[9];
    const float* b3  = (const float*)d_in[10];
    const float* g3  = (const float*)d_in[11];
    const float* be3 = (const float*)d_in[12];
    const float* Wm  = (const float*)d_in[13];
    const float* bm  = (const float*)d_in[14];
    unsigned short* ws = (unsigned short*)d_ws;
    float* out = (float*)d_out;

    conv_w_kernel<<<(WS_ELEMS + 255) / 256, 256, 0, stream>>>(W1, b1, W2, W3, Wm, ws);
    fused_mlp<<<NBLK, 512, 0, stream>>>(x, g1, be1, b2, g2, be2,
                                        b3, g3, be3, bm, ws, out);
}

// Round 8
// 107.785 us; speedup vs baseline: 3.0640x; 1.3963x over previous
//
#include <hip/hip_runtime.h>
#include <hip/hip_bf16.h>

#define BATCH 262144
#define DIN 48
#define HDIM 256
#define DOUT 12
#define EPSV 1e-5f

// 512 threads (8 waves); each wave owns 16 batch rows (1 r-tile).
// Activations TRANSPOSED in registers: C/D of mfma_16x16x32_bf16:
// col = lane&15 = batch row, row(feature) = 4*(lane>>4) + reg.
// Weights for layers 2/3/final use PERMUTED k-order phi(s,q,j) =
// 32s + 16*(j>=4) + 4q + (j&3) so next-layer B-frags are lane-local.
// rt=1 keeps regs <= 128/lane -> 2 blocks/CU resident -> cross-block
// MFMA/VALU phase overlap.
#define ROWS_PER_BLOCK 128
#define NBLK (BATCH / ROWS_PER_BLOCK)

typedef __attribute__((ext_vector_type(4))) float f32x4;
typedef __attribute__((ext_vector_type(8))) short bf16x8;

union FragU { bf16x8 v; unsigned u[4]; };

// ws layout (ushort), FRAGMENT-MAJOR:
//   idx-in-region = ((s*16 + t)*64 + lane)*8 + j
//   W1 region: k = 32s + 8*(lane>>4) + j          (linear)
//   W2/W3/Wm:  k = phi(s, lane>>4, j)             (permuted)
#define W1F_OFF 0          // 2 slabs  (K=64: k<48 -> W1, k==48 -> b1, else 0)
#define W2F_OFF 16384      // 8 slabs
#define W3F_OFF 81920      // 8 slabs
#define WMF_OFF 147456     // 8 slabs of a single t: n = lane&15 (n<12 real)
#define WS_ELEMS 151552

__device__ __forceinline__ unsigned short f2b(float f) {
    union { float f; unsigned u; } v; v.f = f;
    unsigned r = (v.u + 0x7fffu + ((v.u >> 16) & 1u)) >> 16;  // RNE
    return (unsigned short)r;
}

__device__ __forceinline__ unsigned packbf(float a, float b) {
    float2 t; t.x = a; t.y = b;
    __hip_bfloat162 h = __float22bfloat162_rn(t);
    union { __hip_bfloat162 h; unsigned u; } c; c.h = h;
    return c.u;
}

__global__ void conv_w_kernel(const float* __restrict__ W1, const float* __restrict__ b1,
                              const float* __restrict__ W2, const float* __restrict__ W3,
                              const float* __restrict__ Wm,
                              unsigned short* __restrict__ ws) {
    int i = blockIdx.x * 256 + threadIdx.x;
    if (i >= WS_ELEMS) return;
    float v;
    if (i < W2F_OFF) {
        const int j = i & 7, l = (i >> 3) & 63, t = (i >> 9) & 15, s = i >> 13;
        const int n = 16 * t + (l & 15), k = 32 * s + 8 * (l >> 4) + j;  // linear
        v = (k < DIN) ? W1[k * HDIM + n] : (k == DIN ? b1[n] : 0.0f);
    } else if (i < W3F_OFF) {
        const int i2 = i - W2F_OFF;
        const int j = i2 & 7, l = (i2 >> 3) & 63, t = (i2 >> 9) & 15, s = i2 >> 13;
        const int n = 16 * t + (l & 15);
        const int k = 32 * s + ((j >= 4) ? 16 : 0) + 4 * (l >> 4) + (j & 3);  // phi
        v = W2[k * HDIM + n];
    } else if (i < WMF_OFF) {
        const int i3 = i - W3F_OFF;
        const int j = i3 & 7, l = (i3 >> 3) & 63, t = (i3 >> 9) & 15, s = i3 >> 13;
        const int n = 16 * t + (l & 15);
        const int k = 32 * s + ((j >= 4) ? 16 : 0) + 4 * (l >> 4) + (j & 3);  // phi
        v = W3[k * HDIM + n];
    } else {
        const int i4 = i - WMF_OFF;
        const int j = i4 & 7, l = (i4 >> 3) & 63, ks = i4 >> 9;
        const int n = l & 15;
        const int k = 32 * ks + ((j >= 4) ? 16 : 0) + 4 * (l >> 4) + (j & 3); // phi
        v = (n < DOUT) ? Wm[k * DOUT + n] : 0.0f;
    }
    ws[i] = f2b(v);
}

// K-loop over 32-wide k-slabs staged in LDS (reg-staged double buffer,
// 1 barrier/slab). A-frag(t) = slab + t*1024B + lane*16B -> conflict-free.
template<int KS, int KNEXT>
__device__ __forceinline__ void mm_layer(
    f32x4 (&acc)[16], const FragU (&bf)[KS],
    unsigned short (&slab)[2][8192], int& p,
    const unsigned short* __restrict__ wt, const unsigned short* __restrict__ wtnext,
    int tid, int lane)
{
    #pragma unroll
    for (int s = 0; s < KS; s++) {
        int4 R0, R1;
        const bool pf = (s + 1 < KS) || (wtnext != nullptr);
        if (s + 1 < KS) {
            const int4* g = (const int4*)(wt + (s + 1) * 8192 + tid * 16);
            R0 = g[0]; R1 = g[1];
        } else if (wtnext != nullptr) {
            const int4* g = (const int4*)(wtnext + tid * 16);
            R0 = g[0]; R1 = g[1];
        }
        __builtin_amdgcn_s_setprio(1);
        #pragma unroll
        for (int t = 0; t < 16; t++) {
            const bf16x8 A = *(const bf16x8*)&slab[p][(t * 64 + lane) * 8];
            acc[t] = __builtin_amdgcn_mfma_f32_16x16x32_bf16(A, bf[s].v, acc[t], 0, 0, 0);
        }
        __builtin_amdgcn_s_setprio(0);
        if (pf) {
            int4* d = (int4*)&slab[p ^ 1][tid * 16];
            d[0] = R0; d[1] = R1;
        }
        __syncthreads();
        p ^= 1;
    }
}

// LayerNorm + ReLU + bf16 pack. Bias is already in acc (init). B-frags
// lane-local thanks to phi:
//   u[0..1] <- features 32ks+4q+{0..3}    (t = 2ks)
//   u[2..3] <- features 32ks+16+4q+{0..3} (t = 2ks+1)
__device__ __forceinline__ void build_frags(
    const f32x4 (&acc)[16], FragU (&bfo)[8],
    const float2* __restrict__ gbeL, int lane)
{
    const int q = lane >> 4;
    float ss = 0.f, qq = 0.f;
    #pragma unroll
    for (int t = 0; t < 16; t++)
        #pragma unroll
        for (int r = 0; r < 4; r++) {
            const float v = acc[t][r];
            ss += v; qq = fmaf(v, v, qq);
        }
    ss += __shfl_xor(ss, 16); ss += __shfl_xor(ss, 32);
    qq += __shfl_xor(qq, 16); qq += __shfl_xor(qq, 32);
    const float mu = ss * (1.0f / 256.0f);
    const float rs = rsqrtf(fmaxf(qq * (1.0f / 256.0f) - mu * mu, 0.0f) + EPSV);
    const float nb = -mu * rs;
    #pragma unroll
    for (int ks = 0; ks < 8; ks++) {
        const float4 a0 = *(const float4*)&gbeL[32 * ks + 4 * q];
        const float4 a1 = *(const float4*)&gbeL[32 * ks + 4 * q + 2];
        const float4 b0 = *(const float4*)&gbeL[32 * ks + 16 + 4 * q];
        const float4 b1 = *(const float4*)&gbeL[32 * ks + 16 + 4 * q + 2];
        float w00 = fmaxf(fmaf(fmaf(acc[2 * ks][0], rs, nb), a0.x, a0.y), 0.f);
        float w01 = fmaxf(fmaf(fmaf(acc[2 * ks][1], rs, nb), a0.z, a0.w), 0.f);
        float w02 = fmaxf(fmaf(fmaf(acc[2 * ks][2], rs, nb), a1.x, a1.y), 0.f);
        float w03 = fmaxf(fmaf(fmaf(acc[2 * ks][3], rs, nb), a1.z, a1.w), 0.f);
        float w10 = fmaxf(fmaf(fmaf(acc[2 * ks + 1][0], rs, nb), b0.x, b0.y), 0.f);
        float w11 = fmaxf(fmaf(fmaf(acc[2 * ks + 1][1], rs, nb), b0.z, b0.w), 0.f);
        float w12 = fmaxf(fmaf(fmaf(acc[2 * ks + 1][2], rs, nb), b1.x, b1.y), 0.f);
        float w13 = fmaxf(fmaf(fmaf(acc[2 * ks + 1][3], rs, nb), b1.z, b1.w), 0.f);
        bfo[ks].u[0] = packbf(w00, w01);
        bfo[ks].u[1] = packbf(w02, w03);
        bfo[ks].u[2] = packbf(w10, w11);
        bfo[ks].u[3] = packbf(w12, w13);
    }
}

__device__ __forceinline__ void zero_acc(f32x4 (&acc)[16]) {
    #pragma unroll
    for (int t = 0; t < 16; t++)
        acc[t] = (f32x4){0.f, 0.f, 0.f, 0.f};
}

// bias into accumulator init: acc[t][r] = b[16t + 4q + r]
__device__ __forceinline__ void init_acc_bias(f32x4 (&acc)[16],
                                              const float* __restrict__ bt, int q) {
    #pragma unroll
    for (int t = 0; t < 16; t++) {
        const float4 b = *(const float4*)&bt[16 * t + 4 * q];
        acc[t] = (f32x4){b.x, b.y, b.z, b.w};
    }
}

__global__ __launch_bounds__(512, 4) void fused_mlp(
    const float* __restrict__ x,
    const float* __restrict__ g1, const float* __restrict__ be1,
    const float* __restrict__ b2, const float* __restrict__ g2, const float* __restrict__ be2,
    const float* __restrict__ b3, const float* __restrict__ g3, const float* __restrict__ be3,
    const float* __restrict__ bm,
    const unsigned short* __restrict__ ws,
    float* __restrict__ out)
{
    __shared__ unsigned short slab[2][8192];   // 32 KB weight slabs (frag-major)
    __shared__ float2 gbe[3][256];             // 6 KB
    __shared__ float btab[2][256];             // 2 KB
    __shared__ float bmt[16];
    __shared__ float ostage[8][192];           // 6 KB per-wave out staging

    const int tid = threadIdx.x;
    const int wv = tid >> 6, lane = tid & 63;
    const int l15 = lane & 15, q = lane >> 4;
    const int wrow0 = blockIdx.x * ROWS_PER_BLOCK + wv * 16;

    const unsigned short* w1f = ws + W1F_OFF;
    const unsigned short* w2f = ws + W2F_OFF;
    const unsigned short* w3f = ws + W3F_OFF;
    const unsigned short* wmf = ws + WMF_OFF;

    // ---- tables -> LDS ----
    if (tid < 256) {
        const int n = tid;
        gbe[0][n] = make_float2(g1[n], be1[n]);
        gbe[1][n] = make_float2(g2[n], be2[n]);
        gbe[2][n] = make_float2(g3[n], be3[n]);
        btab[0][n] = b2[n];
        btab[1][n] = b3[n];
        if (tid < 16) bmt[tid] = (tid < DOUT) ? bm[tid] : 0.f;
    }
    // ---- stage W1 slab0 ----
    {
        const int4* g = (const int4*)(w1f + tid * 16);
        int4 r0 = g[0], r1 = g[1];
        int4* d = (int4*)&slab[0][tid * 16];
        d[0] = r0; d[1] = r1;
    }
    // ---- x -> layer-1 B-frags (transposed bf16), bias as constant-1 feature ----
    FragU bf1[2];
    {
        const float* xr = x + (size_t)(wrow0 + l15) * DIN;
        const float4 f0 = *(const float4*)(xr + q * 8);
        const float4 f1 = *(const float4*)(xr + q * 8 + 4);
        bf1[0].u[0] = packbf(f0.x, f0.y); bf1[0].u[1] = packbf(f0.z, f0.w);
        bf1[0].u[2] = packbf(f1.x, f1.y); bf1[0].u[3] = packbf(f1.z, f1.w);
        if (q < 2) {
            const float4 f2 = *(const float4*)(xr + 32 + q * 8);
            const float4 f3 = *(const float4*)(xr + 36 + q * 8);
            bf1[1].u[0] = packbf(f2.x, f2.y); bf1[1].u[1] = packbf(f2.z, f2.w);
            bf1[1].u[2] = packbf(f3.x, f3.y); bf1[1].u[3] = packbf(f3.z, f3.w);
        } else if (q == 2) {
            bf1[1].u[0] = 0x00003F80u;  // k=48 -> 1.0 (bias row)
            bf1[1].u[1] = 0u; bf1[1].u[2] = 0u; bf1[1].u[3] = 0u;
        } else {
            bf1[1].u[0] = 0u; bf1[1].u[1] = 0u;
            bf1[1].u[2] = 0u; bf1[1].u[3] = 0u;
        }
    }
    __syncthreads();

    f32x4 acc[16];
    int p = 0;

    zero_acc(acc);                       // layer-1 bias is the k=48 ones-row
    mm_layer<2, 8>(acc, bf1, slab, p, w1f, w2f, tid, lane);
    FragU bf[8];
    build_frags(acc, bf, &gbe[0][0], lane);

    init_acc_bias(acc, &btab[0][0], q);  // b2
    mm_layer<8, 8>(acc, bf, slab, p, w2f, w3f, tid, lane);
    build_frags(acc, bf, &gbe[1][0], lane);

    init_acc_bias(acc, &btab[1][0], q);  // b3
    mm_layer<8, 8>(acc, bf, slab, p, w3f, (const unsigned short*)nullptr, tid, lane);
    build_frags(acc, bf, &gbe[2][0], lane);

    // ---- final layer: Wm frag-major (phi k-order) from global (L2-resident) ----
    f32x4 facc;
    {
        const float4 bm4 = *(const float4*)&bmt[4 * q];
        facc = (f32x4){bm4.x, bm4.y, bm4.z, bm4.w};
    }
    #pragma unroll
    for (int ks = 0; ks < 8; ks++) {
        const bf16x8 A = *(const bf16x8*)&wmf[(ks * 64 + lane) * 8];
        facc = __builtin_amdgcn_mfma_f32_16x16x32_bf16(A, bf[ks].v, facc, 0, 0, 0);
    }
    // tanh -> wave-private LDS staging (row = l15, cols 4q..4q+3 for q<3)
    if (q < 3) {
        float4 o;
        o.x = tanhf(facc[0]);
        o.y = tanhf(facc[1]);
        o.z = tanhf(facc[2]);
        o.w = tanhf(facc[3]);
        *(float4*)&ostage[wv][l15 * 12 + q * 4] = o;
    }
    // coalesced store: 16 rows x 12 f32 = 48 float4 per wave
    float4* og = (float4*)(out + (size_t)wrow0 * DOUT);
    const float4* ov = (const float4*)&ostage[wv][0];
    if (lane < 48) og[lane] = ov[lane];
}

extern "C" void kernel_launch(void* const* d_in, const int* in_sizes, int n_in,
                              void* d_out, int out_size, void* d_ws, size_t ws_size,
                              hipStream_t stream)
{
    const float* x   = (const float*)d_in[0];
    const float* W1  = (const float*)d_in[1];
    const float* b1  = (const float*)d_in[2];
    const float* g1  = (const float*)d_in[3];
    const float* be1 = (const float*)d_in[4];
    const float* W2  = (const float*)d_in[5];
    const float* b2  = (const float*)d_in[6];
    const float* g2  = (const float*)d_in[7];
    const float* be2 = (const float*)d_in[8];
    const float* W3  = (const float*)d_in[9];
    const float* b3  = (const float*)d_in[10];
    const float* g3  = (const float*)d_in[11];
    const float* be3 = (const float*)d_in[12];
    const float* Wm  = (const float*)d_in[13];
    const float* bm  = (const float*)d_in[14];
    unsigned short* ws = (unsigned short*)d_ws;
    float* out = (float*)d_out;

    conv_w_kernel<<<(WS_ELEMS + 255) / 256, 256, 0, stream>>>(W1, b1, W2, W3, Wm, ws);
    fused_mlp<<<NBLK, 512, 0, stream>>>(x, g1, be1, b2, g2, be2,
                                        b3, g3, be3, bm, ws, out);
}

// Round 9
// 105.037 us; speedup vs baseline: 3.1442x; 1.0262x over previous
//
#include <hip/hip_runtime.h>
#include <hip/hip_bf16.h>

#define BATCH 262144
#define DIN 48
#define HDIM 256
#define DOUT 12
#define EPSV 1e-5f

// 256 threads (4 waves); each wave owns 32 batch rows (2 r-tiles of 16).
// Activations TRANSPOSED in registers: C/D of mfma_16x16x32_bf16:
// col = lane&15 = batch row, row(feature) = 4*(lane>>4) + reg.
// Weights for layers 2/3/final use PERMUTED k-order phi(s,q,j) =
// 32s + 16*(j>=4) + 4q + (j&3) so next-layer B-frags are lane-local.
// rt=2 doubles A-frag reuse (32 FLOP per LDS byte) -> LDS-read time halves.
// Slab storage order additionally permuted so staging ds_write_b128s are
// lane-contiguous (conflict-free): quarter h lives at h*4KB + tid*16B.
#define ROWS_PER_BLOCK 128
#define NBLK (BATCH / ROWS_PER_BLOCK)

typedef __attribute__((ext_vector_type(4))) float f32x4;
typedef __attribute__((ext_vector_type(8))) short bf16x8;

union FragU { bf16x8 v; unsigned u[4]; };

// ws layout (ushort):
//   staged regions (W1/W2/W3): per 8192-ushort slab, storage index
//     u = tid*32 + h*8 + j  holds frag-major element fm = h*2048 + tid*8 + j,
//     fm = (t*64 + lane)*8 + jj -> n = 16t + (lane&15),
//     k: W1 linear = 32s + 8*(lane>>4) + jj
//        W2/W3 phi = 32s + 16*(jj>=4) + 4*(lane>>4) + (jj&3)
//   Wm region: ((ks*64 + lane)*8 + j), k = phi, n = lane&15 (n<12 real)
#define W1F_OFF 0          // 2 slabs  (K=64: k<48 -> W1, k==48 -> b1, else 0)
#define W2F_OFF 16384      // 8 slabs
#define W3F_OFF 81920      // 8 slabs
#define WMF_OFF 147456     // 4096
#define WS_ELEMS 151552

__device__ __forceinline__ unsigned short f2b(float f) {
    union { float f; unsigned u; } v; v.f = f;
    unsigned r = (v.u + 0x7fffu + ((v.u >> 16) & 1u)) >> 16;  // RNE
    return (unsigned short)r;
}

__device__ __forceinline__ unsigned packbf(float a, float b) {
    float2 t; t.x = a; t.y = b;
    __hip_bfloat162 h = __float22bfloat162_rn(t);
    union { __hip_bfloat162 h; unsigned u; } c; c.h = h;
    return c.u;
}

__global__ void conv_w_kernel(const float* __restrict__ W1, const float* __restrict__ b1,
                              const float* __restrict__ W2, const float* __restrict__ W3,
                              const float* __restrict__ Wm,
                              unsigned short* __restrict__ ws) {
    int i = blockIdx.x * 256 + threadIdx.x;
    if (i >= WS_ELEMS) return;
    float v;
    if (i < WMF_OFF) {
        // staged region: decode storage -> frag-major
        int base, which;
        if (i < W2F_OFF)      { base = i - W1F_OFF; which = 0; }
        else if (i < W3F_OFF) { base = i - W2F_OFF; which = 1; }
        else                  { base = i - W3F_OFF; which = 2; }
        const int s = base >> 13;
        const int u = base & 8191;
        const int tid = u >> 5;
        const int h = (u >> 3) & 3;
        const int j = u & 7;
        const int fm = h * 2048 + tid * 8 + j;
        const int t = fm >> 9;
        const int l = (fm >> 3) & 63;
        const int jj = fm & 7;
        const int n = 16 * t + (l & 15);
        if (which == 0) {
            const int k = 32 * s + 8 * (l >> 4) + jj;              // linear
            v = (k < DIN) ? W1[k * HDIM + n] : (k == DIN ? b1[n] : 0.0f);
        } else {
            const int k = 32 * s + ((jj >= 4) ? 16 : 0) + 4 * (l >> 4) + (jj & 3);  // phi
            v = (which == 1) ? W2[k * HDIM + n] : W3[k * HDIM + n];
        }
    } else {
        const int i4 = i - WMF_OFF;
        const int j = i4 & 7, l = (i4 >> 3) & 63, ks = i4 >> 9;
        const int n = l & 15;
        const int k = 32 * ks + ((j >= 4) ? 16 : 0) + 4 * (l >> 4) + (j & 3);  // phi
        v = (n < DOUT) ? Wm[k * DOUT + n] : 0.0f;
    }
    ws[i] = f2b(v);
}

// K-loop over 32-wide k-slabs staged in LDS (reg-staged double buffer,
// 1 barrier/slab). A-frag(t) = slab + t*1024B + lane*16B -> conflict-free;
// each A-frag feeds BOTH r-tiles (2 MFMAs per LDS read).
template<int KS>
__device__ __forceinline__ void mm_layer(
    f32x4 (&acc)[2][16], const FragU (&bf)[2][8],
    unsigned short (&slab)[2][8192], int& p,
    const unsigned short* __restrict__ wt, const unsigned short* __restrict__ wtnext,
    int tid, int lane)
{
    #pragma unroll
    for (int s = 0; s < KS; s++) {
        int4 R0, R1, R2, R3;
        const bool pf = (s + 1 < KS) || (wtnext != nullptr);
        if (s + 1 < KS) {
            const int4* g = (const int4*)(wt + (s + 1) * 8192 + tid * 32);
            R0 = g[0]; R1 = g[1]; R2 = g[2]; R3 = g[3];
        } else if (wtnext != nullptr) {
            const int4* g = (const int4*)(wtnext + tid * 32);
            R0 = g[0]; R1 = g[1]; R2 = g[2]; R3 = g[3];
        }
        __builtin_amdgcn_s_setprio(1);
        #pragma unroll
        for (int t = 0; t < 16; t++) {
            const bf16x8 A = *(const bf16x8*)&slab[p][(t * 64 + lane) * 8];
            acc[0][t] = __builtin_amdgcn_mfma_f32_16x16x32_bf16(A, bf[0][s].v, acc[0][t], 0, 0, 0);
            acc[1][t] = __builtin_amdgcn_mfma_f32_16x16x32_bf16(A, bf[1][s].v, acc[1][t], 0, 0, 0);
        }
        __builtin_amdgcn_s_setprio(0);
        if (pf) {
            unsigned short* sb = &slab[p ^ 1][0];
            *(int4*)&sb[tid * 8]        = R0;
            *(int4*)&sb[2048 + tid * 8] = R1;
            *(int4*)&sb[4096 + tid * 8] = R2;
            *(int4*)&sb[6144 + tid * 8] = R3;
        }
        __syncthreads();
        p ^= 1;
    }
}

// LayerNorm + ReLU + bf16 pack (bias already in acc). B-frags lane-local
// thanks to phi:
//   u[0..1] <- features 32ks+4q+{0..3}    (t = 2ks)
//   u[2..3] <- features 32ks+16+4q+{0..3} (t = 2ks+1)
__device__ __forceinline__ void build_frags(
    const f32x4 (&acc)[2][16], FragU (&bfo)[2][8],
    const float2* __restrict__ gbeL, int lane)
{
    const int q = lane >> 4;
    #pragma unroll
    for (int rt = 0; rt < 2; rt++) {
        float ss = 0.f, qq = 0.f;
        #pragma unroll
        for (int t = 0; t < 16; t++)
            #pragma unroll
            for (int r = 0; r < 4; r++) {
                const float v = acc[rt][t][r];
                ss += v; qq = fmaf(v, v, qq);
            }
        ss += __shfl_xor(ss, 16); ss += __shfl_xor(ss, 32);
        qq += __shfl_xor(qq, 16); qq += __shfl_xor(qq, 32);
        const float mu = ss * (1.0f / 256.0f);
        const float rs = rsqrtf(fmaxf(qq * (1.0f / 256.0f) - mu * mu, 0.0f) + EPSV);
        const float nb = -mu * rs;
        #pragma unroll
        for (int ks = 0; ks < 8; ks++) {
            const float4 a0 = *(const float4*)&gbeL[32 * ks + 4 * q];
            const float4 a1 = *(const float4*)&gbeL[32 * ks + 4 * q + 2];
            const float4 b0 = *(const float4*)&gbeL[32 * ks + 16 + 4 * q];
            const float4 b1 = *(const float4*)&gbeL[32 * ks + 16 + 4 * q + 2];
            float w00 = fmaxf(fmaf(fmaf(acc[rt][2 * ks][0], rs, nb), a0.x, a0.y), 0.f);
            float w01 = fmaxf(fmaf(fmaf(acc[rt][2 * ks][1], rs, nb), a0.z, a0.w), 0.f);
            float w02 = fmaxf(fmaf(fmaf(acc[rt][2 * ks][2], rs, nb), a1.x, a1.y), 0.f);
            float w03 = fmaxf(fmaf(fmaf(acc[rt][2 * ks][3], rs, nb), a1.z, a1.w), 0.f);
            float w10 = fmaxf(fmaf(fmaf(acc[rt][2 * ks + 1][0], rs, nb), b0.x, b0.y), 0.f);
            float w11 = fmaxf(fmaf(fmaf(acc[rt][2 * ks + 1][1], rs, nb), b0.z, b0.w), 0.f);
            float w12 = fmaxf(fmaf(fmaf(acc[rt][2 * ks + 1][2], rs, nb), b1.x, b1.y), 0.f);
            float w13 = fmaxf(fmaf(fmaf(acc[rt][2 * ks + 1][3], rs, nb), b1.z, b1.w), 0.f);
            bfo[rt][ks].u[0] = packbf(w00, w01);
            bfo[rt][ks].u[1] = packbf(w02, w03);
            bfo[rt][ks].u[2] = packbf(w10, w11);
            bfo[rt][ks].u[3] = packbf(w12, w13);
        }
    }
}

__device__ __forceinline__ void zero_acc(f32x4 (&acc)[2][16]) {
    #pragma unroll
    for (int rt = 0; rt < 2; rt++)
        #pragma unroll
        for (int t = 0; t < 16; t++)
            acc[rt][t] = (f32x4){0.f, 0.f, 0.f, 0.f};
}

// bias into accumulator init: acc[rt][t][r] = b[16t + 4q + r]
__device__ __forceinline__ void init_acc_bias(f32x4 (&acc)[2][16],
                                              const float* __restrict__ bt, int q) {
    #pragma unroll
    for (int t = 0; t < 16; t++) {
        const float4 b = *(const float4*)&bt[16 * t + 4 * q];
        acc[0][t] = (f32x4){b.x, b.y, b.z, b.w};
        acc[1][t] = (f32x4){b.x, b.y, b.z, b.w};
    }
}

__global__ __launch_bounds__(256, 2) void fused_mlp(
    const float* __restrict__ x,
    const float* __restrict__ g1, const float* __restrict__ be1,
    const float* __restrict__ b2, const float* __restrict__ g2, const float* __restrict__ be2,
    const float* __restrict__ b3, const float* __restrict__ g3, const float* __restrict__ be3,
    const float* __restrict__ bm,
    const unsigned short* __restrict__ ws,
    float* __restrict__ out)
{
    __shared__ unsigned short slab[2][8192];   // 32 KB weight slabs
    __shared__ float2 gbe[3][256];             // 6 KB
    __shared__ float btab[2][256];             // 2 KB
    __shared__ float bmt[16];
    __shared__ float ostage[4][384];           // 6 KB per-wave out staging

    const int tid = threadIdx.x;
    const int wv = tid >> 6, lane = tid & 63;
    const int l15 = lane & 15, q = lane >> 4;
    const int wrow0 = blockIdx.x * ROWS_PER_BLOCK + wv * 32;

    const unsigned short* w1f = ws + W1F_OFF;
    const unsigned short* w2f = ws + W2F_OFF;
    const unsigned short* w3f = ws + W3F_OFF;
    const unsigned short* wmf = ws + WMF_OFF;

    // ---- tables -> LDS ----
    {
        const int n = tid;
        gbe[0][n] = make_float2(g1[n], be1[n]);
        gbe[1][n] = make_float2(g2[n], be2[n]);
        gbe[2][n] = make_float2(g3[n], be3[n]);
        btab[0][n] = b2[n];
        btab[1][n] = b3[n];
        if (tid < 16) bmt[tid] = (tid < DOUT) ? bm[tid] : 0.f;
    }
    // ---- stage W1 slab0 (conflict-free quarters) ----
    {
        const int4* g = (const int4*)(w1f + tid * 32);
        int4 r0 = g[0], r1 = g[1], r2 = g[2], r3 = g[3];
        unsigned short* sb = &slab[0][0];
        *(int4*)&sb[tid * 8]        = r0;
        *(int4*)&sb[2048 + tid * 8] = r1;
        *(int4*)&sb[4096 + tid * 8] = r2;
        *(int4*)&sb[6144 + tid * 8] = r3;
    }
    // ---- x -> layer-1 B-frags (into bf[rt][0..1]), bias = k=48 ones-row ----
    FragU bf[2][8];
    #pragma unroll
    for (int rt = 0; rt < 2; rt++) {
        const float* xr = x + (size_t)(wrow0 + rt * 16 + l15) * DIN;
        const float4 f0 = *(const float4*)(xr + q * 8);
        const float4 f1 = *(const float4*)(xr + q * 8 + 4);
        bf[rt][0].u[0] = packbf(f0.x, f0.y); bf[rt][0].u[1] = packbf(f0.z, f0.w);
        bf[rt][0].u[2] = packbf(f1.x, f1.y); bf[rt][0].u[3] = packbf(f1.z, f1.w);
        if (q < 2) {
            const float4 f2 = *(const float4*)(xr + 32 + q * 8);
            const float4 f3 = *(const float4*)(xr + 36 + q * 8);
            bf[rt][1].u[0] = packbf(f2.x, f2.y); bf[rt][1].u[1] = packbf(f2.z, f2.w);
            bf[rt][1].u[2] = packbf(f3.x, f3.y); bf[rt][1].u[3] = packbf(f3.z, f3.w);
        } else if (q == 2) {
            bf[rt][1].u[0] = 0x00003F80u;  // k=48 -> 1.0 (bias row)
            bf[rt][1].u[1] = 0u; bf[rt][1].u[2] = 0u; bf[rt][1].u[3] = 0u;
        } else {
            bf[rt][1].u[0] = 0u; bf[rt][1].u[1] = 0u;
            bf[rt][1].u[2] = 0u; bf[rt][1].u[3] = 0u;
        }
    }
    __syncthreads();

    f32x4 acc[2][16];
    int p = 0;

    zero_acc(acc);                       // layer-1 bias is the k=48 ones-row
    mm_layer<2>(acc, bf, slab, p, w1f, w2f, tid, lane);
    build_frags(acc, bf, &gbe[0][0], lane);

    init_acc_bias(acc, &btab[0][0], q);  // b2
    mm_layer<8>(acc, bf, slab, p, w2f, w3f, tid, lane);
    build_frags(acc, bf, &gbe[1][0], lane);

    init_acc_bias(acc, &btab[1][0], q);  // b3
    mm_layer<8>(acc, bf, slab, p, w3f, (const unsigned short*)nullptr, tid, lane);
    build_frags(acc, bf, &gbe[2][0], lane);

    // ---- final layer: Wm frag-major (phi k-order) from global (L2-resident);
    //      each A-read feeds both r-tiles ----
    f32x4 facc[2];
    {
        const float4 bm4 = *(const float4*)&bmt[4 * q];
        facc[0] = (f32x4){bm4.x, bm4.y, bm4.z, bm4.w};
        facc[1] = facc[0];
    }
    #pragma unroll
    for (int ks = 0; ks < 8; ks++) {
        const bf16x8 A = *(const bf16x8*)&wmf[(ks * 64 + lane) * 8];
        facc[0] = __builtin_amdgcn_mfma_f32_16x16x32_bf16(A, bf[0][ks].v, facc[0], 0, 0, 0);
        facc[1] = __builtin_amdgcn_mfma_f32_16x16x32_bf16(A, bf[1][ks].v, facc[1], 0, 0, 0);
    }
    // tanh -> wave-private LDS staging (row = rt*16+l15, cols 4q..4q+3 for q<3)
    if (q < 3) {
        #pragma unroll
        for (int rt = 0; rt < 2; rt++) {
            float4 o;
            o.x = tanhf(facc[rt][0]);
            o.y = tanhf(facc[rt][1]);
            o.z = tanhf(facc[rt][2]);
            o.w = tanhf(facc[rt][3]);
            *(float4*)&ostage[wv][(rt * 16 + l15) * 12 + q * 4] = o;
        }
    }
    // coalesced store: 32 rows x 12 f32 = 96 float4 per wave
    float4* og = (float4*)(out + (size_t)wrow0 * DOUT);
    const float4* ov = (const float4*)&ostage[wv][0];
    og[lane] = ov[lane];
    if (lane < 32) og[64 + lane] = ov[64 + lane];
}

extern "C" void kernel_launch(void* const* d_in, const int* in_sizes, int n_in,
                              void* d_out, int out_size, void* d_ws, size_t ws_size,
                              hipStream_t stream)
{
    const float* x   = (const float*)d_in[0];
    const float* W1  = (const float*)d_in[1];
    const float* b1  = (const float*)d_in[2];
    const float* g1  = (const float*)d_in[3];
    const float* be1 = (const float*)d_in[4];
    const float* W2  = (const float*)d_in[5];
    const float* b2  = (const float*)d_in[6];
    const float* g2  = (const float*)d_in[7];
    const float* be2 = (const float*)d_in[8];
    const float* W3  = (const float*)d_in[9];
    const float* b3  = (const float*)d_in[10];
    const float* g3  = (const float*)d_in[11];
    const float* be3 = (const float*)d_in[12];
    const float* Wm  = (const float*)d_in[13];
    const float* bm  = (const float*)d_in[14];
    unsigned short* ws = (unsigned short*)d_ws;
    float* out = (float*)d_out;

    conv_w_kernel<<<(WS_ELEMS + 255) / 256, 256, 0, stream>>>(W1, b1, W2, W3, Wm, ws);
    fused_mlp<<<NBLK, 256, 0, stream>>>(x, g1, be1, b2, g2, be2,
                                        b3, g3, be3, bm, ws, out);
}

// Round 10
// 103.001 us; speedup vs baseline: 3.2063x; 1.0198x over previous
//
#include <hip/hip_runtime.h>
#include <hip/hip_bf16.h>

#define BATCH 262144
#define DIN 48
#define HDIM 256
#define DOUT 12
#define EPSV 1e-5f

// 256 threads (4 waves); each wave owns 32 batch rows (2 r-tiles of 16).
// Activations TRANSPOSED in registers: C/D of mfma_16x16x32_bf16:
// col = lane&15 = batch row, row(feature) = 4*(lane>>4) + reg.
// Weights for layers 2/3/final use PERMUTED k-order phi(s,q,j) =
// 32s + 16*(j>=4) + 4q + (j&3) so next-layer B-frags are lane-local.
// Staging: global_load_lds (16B) direct to LDS, 2-slab (32KB) pairs,
// double-buffered -> 9 barriers total instead of 18.
#define ROWS_PER_BLOCK 128
#define NBLK (BATCH / ROWS_PER_BLOCK)

typedef __attribute__((ext_vector_type(4))) float f32x4;
typedef __attribute__((ext_vector_type(8))) short bf16x8;

union FragU { bf16x8 v; unsigned u[4]; };

// ws layout (ushort), FRAGMENT-MAJOR (plain; no storage permute needed since
// global_load_lds writes LDS linearly):
//   idx-in-region = ((s*16 + t)*64 + lane)*8 + j
//   W1 region: k = 32s + 8*(lane>>4) + j          (linear)
//   W2/W3/Wm:  k = phi(s, lane>>4, j)             (permuted)
#define W1F_OFF 0          // 2 slabs  (K=64: k<48 -> W1, k==48 -> b1, else 0)
#define W2F_OFF 16384      // 8 slabs
#define W3F_OFF 81920      // 8 slabs
#define WMF_OFF 147456     // 4096
#define WS_ELEMS 151552

__device__ __forceinline__ unsigned short f2b(float f) {
    union { float f; unsigned u; } v; v.f = f;
    unsigned r = (v.u + 0x7fffu + ((v.u >> 16) & 1u)) >> 16;  // RNE
    return (unsigned short)r;
}

__device__ __forceinline__ unsigned packbf(float a, float b) {
    float2 t; t.x = a; t.y = b;
    __hip_bfloat162 h = __float22bfloat162_rn(t);
    union { __hip_bfloat162 h; unsigned u; } c; c.h = h;
    return c.u;
}

__device__ __forceinline__ float fast_tanh(float x) {
    const float t = __expf(2.0f * x);                       // v_mul + v_exp
    return fmaf(-2.0f, __builtin_amdgcn_rcpf(t + 1.0f), 1.0f);
}

__global__ void conv_w_kernel(const float* __restrict__ W1, const float* __restrict__ b1,
                              const float* __restrict__ W2, const float* __restrict__ W3,
                              const float* __restrict__ Wm,
                              unsigned short* __restrict__ ws) {
    int i = blockIdx.x * 256 + threadIdx.x;
    if (i >= WS_ELEMS) return;
    float v;
    if (i < W2F_OFF) {
        const int j = i & 7, l = (i >> 3) & 63, t = (i >> 9) & 15, s = i >> 13;
        const int n = 16 * t + (l & 15), k = 32 * s + 8 * (l >> 4) + j;  // linear
        v = (k < DIN) ? W1[k * HDIM + n] : (k == DIN ? b1[n] : 0.0f);
    } else if (i < W3F_OFF) {
        const int i2 = i - W2F_OFF;
        const int j = i2 & 7, l = (i2 >> 3) & 63, t = (i2 >> 9) & 15, s = i2 >> 13;
        const int n = 16 * t + (l & 15);
        const int k = 32 * s + ((j >= 4) ? 16 : 0) + 4 * (l >> 4) + (j & 3);  // phi
        v = W2[k * HDIM + n];
    } else if (i < WMF_OFF) {
        const int i3 = i - W3F_OFF;
        const int j = i3 & 7, l = (i3 >> 3) & 63, t = (i3 >> 9) & 15, s = i3 >> 13;
        const int n = 16 * t + (l & 15);
        const int k = 32 * s + ((j >= 4) ? 16 : 0) + 4 * (l >> 4) + (j & 3);  // phi
        v = W3[k * HDIM + n];
    } else {
        const int i4 = i - WMF_OFF;
        const int j = i4 & 7, l = (i4 >> 3) & 63, ks = i4 >> 9;
        const int n = l & 15;
        const int k = 32 * ks + ((j >= 4) ? 16 : 0) + 4 * (l >> 4) + (j & 3); // phi
        v = (n < DOUT) ? Wm[k * DOUT + n] : 0.0f;
    }
    ws[i] = f2b(v);
}

// async 16B global->LDS copy (HW DMA; dest must be base + lane*16, which it is)
__device__ __forceinline__ void gll16(const void* g, void* l) {
    __builtin_amdgcn_global_load_lds(
        (const __attribute__((address_space(1))) unsigned int*)g,
        (__attribute__((address_space(3))) unsigned int*)l, 16, 0, 0);
}

// stage one 32KB pair (2 slabs): 8 chunks of 4KB, each lane-contiguous
__device__ __forceinline__ void stage_pair(const unsigned short* __restrict__ src,
                                           unsigned short* dst, int tid) {
    const char* g = (const char*)src + tid * 16;
    char* l = (char*)dst + tid * 16;
    #pragma unroll
    for (int c = 0; c < 8; c++)
        gll16(g + c * 4096, l + c * 4096);
}

// K-loop over 64-wide k-pairs staged in LDS (global_load_lds double buffer,
// 1 barrier/pair). A-frag(t) = buf + h*16KB + t*1KB + lane*16B -> conflict-free;
// each A-frag feeds BOTH r-tiles (2 MFMAs per LDS read).
template<int NP>
__device__ __forceinline__ void mm_layer(
    f32x4 (&acc)[2][16], const FragU (&bf)[2][8],
    unsigned short (&buf)[2][16384], int& p,
    const unsigned short* __restrict__ wt, const unsigned short* __restrict__ wtnext,
    int tid, int lane)
{
    #pragma unroll
    for (int pp = 0; pp < NP; pp++) {
        const unsigned short* nxt = (pp + 1 < NP) ? (wt + (pp + 1) * 16384) : wtnext;
        if (nxt) stage_pair(nxt, &buf[p ^ 1][0], tid);   // issue before MFMA window
        __builtin_amdgcn_s_setprio(1);
        #pragma unroll
        for (int h = 0; h < 2; h++) {
            #pragma unroll
            for (int t = 0; t < 16; t++) {
                const bf16x8 A = *(const bf16x8*)&buf[p][h * 8192 + (t * 64 + lane) * 8];
                acc[0][t] = __builtin_amdgcn_mfma_f32_16x16x32_bf16(A, bf[0][2 * pp + h].v, acc[0][t], 0, 0, 0);
                acc[1][t] = __builtin_amdgcn_mfma_f32_16x16x32_bf16(A, bf[1][2 * pp + h].v, acc[1][t], 0, 0, 0);
            }
        }
        __builtin_amdgcn_s_setprio(0);
        __syncthreads();   // drains vmcnt -> staged pair valid; read buffer free
        p ^= 1;
    }
}

// LayerNorm + ReLU + bf16 pack (bias already in acc). B-frags lane-local
// thanks to phi:
//   u[0..1] <- features 32ks+4q+{0..3}    (t = 2ks)
//   u[2..3] <- features 32ks+16+4q+{0..3} (t = 2ks+1)
__device__ __forceinline__ void build_frags(
    const f32x4 (&acc)[2][16], FragU (&bfo)[2][8],
    const float2* __restrict__ gbeL, int lane)
{
    const int q = lane >> 4;
    #pragma unroll
    for (int rt = 0; rt < 2; rt++) {
        float ss = 0.f, qq = 0.f;
        #pragma unroll
        for (int t = 0; t < 16; t++)
            #pragma unroll
            for (int r = 0; r < 4; r++) {
                const float v = acc[rt][t][r];
                ss += v; qq = fmaf(v, v, qq);
            }
        ss += __shfl_xor(ss, 16); ss += __shfl_xor(ss, 32);
        qq += __shfl_xor(qq, 16); qq += __shfl_xor(qq, 32);
        const float mu = ss * (1.0f / 256.0f);
        const float rs = __builtin_amdgcn_rsqf(
            fmaxf(qq * (1.0f / 256.0f) - mu * mu, 0.0f) + EPSV);
        const float nb = -mu * rs;
        #pragma unroll
        for (int ks = 0; ks < 8; ks++) {
            const float4 a0 = *(const float4*)&gbeL[32 * ks + 4 * q];
            const float4 a1 = *(const float4*)&gbeL[32 * ks + 4 * q + 2];
            const float4 b0 = *(const float4*)&gbeL[32 * ks + 16 + 4 * q];
            const float4 b1 = *(const float4*)&gbeL[32 * ks + 16 + 4 * q + 2];
            float w00 = fmaxf(fmaf(fmaf(acc[rt][2 * ks][0], rs, nb), a0.x, a0.y), 0.f);
            float w01 = fmaxf(fmaf(fmaf(acc[rt][2 * ks][1], rs, nb), a0.z, a0.w), 0.f);
            float w02 = fmaxf(fmaf(fmaf(acc[rt][2 * ks][2], rs, nb), a1.x, a1.y), 0.f);
            float w03 = fmaxf(fmaf(fmaf(acc[rt][2 * ks][3], rs, nb), a1.z, a1.w), 0.f);
            float w10 = fmaxf(fmaf(fmaf(acc[rt][2 * ks + 1][0], rs, nb), b0.x, b0.y), 0.f);
            float w11 = fmaxf(fmaf(fmaf(acc[rt][2 * ks + 1][1], rs, nb), b0.z, b0.w), 0.f);
            float w12 = fmaxf(fmaf(fmaf(acc[rt][2 * ks + 1][2], rs, nb), b1.x, b1.y), 0.f);
            float w13 = fmaxf(fmaf(fmaf(acc[rt][2 * ks + 1][3], rs, nb), b1.z, b1.w), 0.f);
            bfo[rt][ks].u[0] = packbf(w00, w01);
            bfo[rt][ks].u[1] = packbf(w02, w03);
            bfo[rt][ks].u[2] = packbf(w10, w11);
            bfo[rt][ks].u[3] = packbf(w12, w13);
        }
    }
}

__device__ __forceinline__ void zero_acc(f32x4 (&acc)[2][16]) {
    #pragma unroll
    for (int rt = 0; rt < 2; rt++)
        #pragma unroll
        for (int t = 0; t < 16; t++)
            acc[rt][t] = (f32x4){0.f, 0.f, 0.f, 0.f};
}

// bias into accumulator init: acc[rt][t][r] = b[16t + 4q + r]
__device__ __forceinline__ void init_acc_bias(f32x4 (&acc)[2][16],
                                              const float* __restrict__ bt, int q) {
    #pragma unroll
    for (int t = 0; t < 16; t++) {
        const float4 b = *(const float4*)&bt[16 * t + 4 * q];
        acc[0][t] = (f32x4){b.x, b.y, b.z, b.w};
        acc[1][t] = (f32x4){b.x, b.y, b.z, b.w};
    }
}

__global__ __launch_bounds__(256, 2) void fused_mlp(
    const float* __restrict__ x,
    const float* __restrict__ g1, const float* __restrict__ be1,
    const float* __restrict__ b2, const float* __restrict__ g2, const float* __restrict__ be2,
    const float* __restrict__ b3, const float* __restrict__ g3, const float* __restrict__ be3,
    const float* __restrict__ bm,
    const unsigned short* __restrict__ ws,
    float* __restrict__ out)
{
    __shared__ unsigned short buf[2][16384];   // 64 KB: two 32KB pair buffers
    __shared__ float2 gbe[3][256];             // 6 KB
    __shared__ float btab[2][256];             // 2 KB
    __shared__ float bmt[16];
    __shared__ float ostage[4][384];           // 6 KB  -> 79.9 KB total (2 blk/CU)

    const int tid = threadIdx.x;
    const int wv = tid >> 6, lane = tid & 63;
    const int l15 = lane & 15, q = lane >> 4;
    const int wrow0 = blockIdx.x * ROWS_PER_BLOCK + wv * 32;

    const unsigned short* w1f = ws + W1F_OFF;
    const unsigned short* w2f = ws + W2F_OFF;
    const unsigned short* w3f = ws + W3F_OFF;
    const unsigned short* wmf = ws + WMF_OFF;

    // ---- stage W1 pair (both slabs) via async DMA; tables -> LDS meanwhile ----
    stage_pair(w1f, &buf[0][0], tid);
    {
        const int n = tid;
        gbe[0][n] = make_float2(g1[n], be1[n]);
        gbe[1][n] = make_float2(g2[n], be2[n]);
        gbe[2][n] = make_float2(g3[n], be3[n]);
        btab[0][n] = b2[n];
        btab[1][n] = b3[n];
        if (tid < 16) bmt[tid] = (tid < DOUT) ? bm[tid] : 0.f;
    }
    // ---- x -> layer-1 B-frags (into bf[rt][0..1]), bias = k=48 ones-row ----
    FragU bf[2][8];
    #pragma unroll
    for (int rt = 0; rt < 2; rt++) {
        const float* xr = x + (size_t)(wrow0 + rt * 16 + l15) * DIN;
        const float4 f0 = *(const float4*)(xr + q * 8);
        const float4 f1 = *(const float4*)(xr + q * 8 + 4);
        bf[rt][0].u[0] = packbf(f0.x, f0.y); bf[rt][0].u[1] = packbf(f0.z, f0.w);
        bf[rt][0].u[2] = packbf(f1.x, f1.y); bf[rt][0].u[3] = packbf(f1.z, f1.w);
        if (q < 2) {
            const float4 f2 = *(const float4*)(xr + 32 + q * 8);
            const float4 f3 = *(const float4*)(xr + 36 + q * 8);
            bf[rt][1].u[0] = packbf(f2.x, f2.y); bf[rt][1].u[1] = packbf(f2.z, f2.w);
            bf[rt][1].u[2] = packbf(f3.x, f3.y); bf[rt][1].u[3] = packbf(f3.z, f3.w);
        } else if (q == 2) {
            bf[rt][1].u[0] = 0x00003F80u;  // k=48 -> 1.0 (bias row)
            bf[rt][1].u[1] = 0u; bf[rt][1].u[2] = 0u; bf[rt][1].u[3] = 0u;
        } else {
            bf[rt][1].u[0] = 0u; bf[rt][1].u[1] = 0u;
            bf[rt][1].u[2] = 0u; bf[rt][1].u[3] = 0u;
        }
    }
    __syncthreads();   // drains W1 DMA

    f32x4 acc[2][16];
    int p = 0;

    zero_acc(acc);                       // layer-1 bias is the k=48 ones-row
    mm_layer<1>(acc, bf, buf, p, w1f, w2f, tid, lane);
    build_frags(acc, bf, &gbe[0][0], lane);

    init_acc_bias(acc, &btab[0][0], q);  // b2
    mm_layer<4>(acc, bf, buf, p, w2f, w3f, tid, lane);
    build_frags(acc, bf, &gbe[1][0], lane);

    init_acc_bias(acc, &btab[1][0], q);  // b3
    mm_layer<4>(acc, bf, buf, p, w3f, (const unsigned short*)nullptr, tid, lane);
    build_frags(acc, bf, &gbe[2][0], lane);

    // ---- final layer: Wm frag-major (phi k-order) from global (L2-resident);
    //      each A-read feeds both r-tiles ----
    f32x4 facc[2];
    {
        const float4 bm4 = *(const float4*)&bmt[4 * q];
        facc[0] = (f32x4){bm4.x, bm4.y, bm4.z, bm4.w};
        facc[1] = facc[0];
    }
    #pragma unroll
    for (int ks = 0; ks < 8; ks++) {
        const bf16x8 A = *(const bf16x8*)&wmf[(ks * 64 + lane) * 8];
        facc[0] = __builtin_amdgcn_mfma_f32_16x16x32_bf16(A, bf[0][ks].v, facc[0], 0, 0, 0);
        facc[1] = __builtin_amdgcn_mfma_f32_16x16x32_bf16(A, bf[1][ks].v, facc[1], 0, 0, 0);
    }
    // tanh -> wave-private LDS staging (row = rt*16+l15, cols 4q..4q+3 for q<3)
    if (q < 3) {
        #pragma unroll
        for (int rt = 0; rt < 2; rt++) {
            float4 o;
            o.x = fast_tanh(facc[rt][0]);
            o.y = fast_tanh(facc[rt][1]);
            o.z = fast_tanh(facc[rt][2]);
            o.w = fast_tanh(facc[rt][3]);
            *(float4*)&ostage[wv][(rt * 16 + l15) * 12 + q * 4] = o;
        }
    }
    // coalesced store: 32 rows x 12 f32 = 96 float4 per wave
    float4* og = (float4*)(out + (size_t)wrow0 * DOUT);
    const float4* ov = (const float4*)&ostage[wv][0];
    og[lane] = ov[lane];
    if (lane < 32) og[64 + lane] = ov[64 + lane];
}

extern "C" void kernel_launch(void* const* d_in, const int* in_sizes, int n_in,
                              void* d_out, int out_size, void* d_ws, size_t ws_size,
                              hipStream_t stream)
{
    const float* x   = (const float*)d_in[0];
    const float* W1  = (const float*)d_in[1];
    const float* b1  = (const float*)d_in[2];
    const float* g1  = (const float*)d_in[3];
    const float* be1 = (const float*)d_in[4];
    const float* W2  = (const float*)d_in[5];
    const float* b2  = (const float*)d_in[6];
    const float* g2  = (const float*)d_in[7];
    const float* be2 = (const float*)d_in[8];
    const float* W3  = (const float*)d_in[9];
    const float* b3  = (const float*)d_in[10];
    const float* g3  = (const float*)d_in[11];
    const float* be3 = (const float*)d_in[12];
    const float* Wm  = (const float*)d_in[13];
    const float* bm  = (const float*)d_in[14];
    unsigned short* ws = (unsigned short*)d_ws;
    float* out = (float*)d_out;

    conv_w_kernel<<<(WS_ELEMS + 255) / 256, 256, 0, stream>>>(W1, b1, W2, W3, Wm, ws);
    fused_mlp<<<NBLK, 256, 0, stream>>>(x, g1, be1, b2, g2, be2,
                                        b3, g3, be3, bm, ws, out);
}

// Round 11
// 100.540 us; speedup vs baseline: 3.2848x; 1.0245x over previous
//
#include <hip/hip_runtime.h>
#include <hip/hip_bf16.h>

#define BATCH 262144
#define DIN 48
#define HDIM 256
#define DOUT 12
#define EPSV 1e-5f

// 256 threads (4 waves); each wave owns 32 batch rows (2 r-tiles of 16).
// Activations TRANSPOSED in registers. Weights for layers 2/3/final use
// PERMUTED k-order phi so next-layer B-frags are lane-local.
// NEW: slab-granular (16KB) quad-buffered staging with counted
// s_waitcnt vmcnt(8) + raw s_barrier -> staging loads never drain (T3/T4),
// and packed-f32 (v_pk_*) LayerNorm math (biggest VALU block ~halved).
#define ROWS_PER_BLOCK 128
#define NBLK (BATCH / ROWS_PER_BLOCK)

typedef __attribute__((ext_vector_type(4))) float f32x4;
typedef __attribute__((ext_vector_type(2))) float f32x2;
typedef __attribute__((ext_vector_type(8))) short bf16x8;

union FragU { bf16x8 v; unsigned u[4]; };

// ws layout (ushort), FRAGMENT-MAJOR:
//   idx-in-region = ((s*16 + t)*64 + lane)*8 + j
//   W1 region: k = 32s + 8*(lane>>4) + j          (linear)
//   W2/W3/Wm:  k = phi(s, lane>>4, j)             (permuted)
#define W1F_OFF 0          // 2 slabs  (K=64: k<48 -> W1, k==48 -> b1, else 0)
#define W2F_OFF 16384      // 8 slabs
#define W3F_OFF 81920      // 8 slabs
#define WMF_OFF 147456     // 4096
#define WS_ELEMS 151552

#define WAITV(n) asm volatile("s_waitcnt vmcnt(" #n ")" ::: "memory")

__device__ __forceinline__ unsigned short f2b(float f) {
    union { float f; unsigned u; } v; v.f = f;
    unsigned r = (v.u + 0x7fffu + ((v.u >> 16) & 1u)) >> 16;  // RNE
    return (unsigned short)r;
}

__device__ __forceinline__ unsigned packbf(float a, float b) {
    float2 t; t.x = a; t.y = b;
    __hip_bfloat162 h = __float22bfloat162_rn(t);
    union { __hip_bfloat162 h; unsigned u; } c; c.h = h;
    return c.u;
}

__device__ __forceinline__ float fast_tanh(float x) {
    const float t = __expf(2.0f * x);
    return fmaf(-2.0f, __builtin_amdgcn_rcpf(t + 1.0f), 1.0f);
}

__global__ void conv_w_kernel(const float* __restrict__ W1, const float* __restrict__ b1,
                              const float* __restrict__ W2, const float* __restrict__ W3,
                              const float* __restrict__ Wm,
                              unsigned short* __restrict__ ws) {
    int i = blockIdx.x * 256 + threadIdx.x;
    if (i >= WS_ELEMS) return;
    float v;
    if (i < W2F_OFF) {
        const int j = i & 7, l = (i >> 3) & 63, t = (i >> 9) & 15, s = i >> 13;
        const int n = 16 * t + (l & 15), k = 32 * s + 8 * (l >> 4) + j;  // linear
        v = (k < DIN) ? W1[k * HDIM + n] : (k == DIN ? b1[n] : 0.0f);
    } else if (i < W3F_OFF) {
        const int i2 = i - W2F_OFF;
        const int j = i2 & 7, l = (i2 >> 3) & 63, t = (i2 >> 9) & 15, s = i2 >> 13;
        const int n = 16 * t + (l & 15);
        const int k = 32 * s + ((j >= 4) ? 16 : 0) + 4 * (l >> 4) + (j & 3);  // phi
        v = W2[k * HDIM + n];
    } else if (i < WMF_OFF) {
        const int i3 = i - W3F_OFF;
        const int j = i3 & 7, l = (i3 >> 3) & 63, t = (i3 >> 9) & 15, s = i3 >> 13;
        const int n = 16 * t + (l & 15);
        const int k = 32 * s + ((j >= 4) ? 16 : 0) + 4 * (l >> 4) + (j & 3);  // phi
        v = W3[k * HDIM + n];
    } else {
        const int i4 = i - WMF_OFF;
        const int j = i4 & 7, l = (i4 >> 3) & 63, ks = i4 >> 9;
        const int n = l & 15;
        const int k = 32 * ks + ((j >= 4) ? 16 : 0) + 4 * (l >> 4) + (j & 3); // phi
        v = (n < DOUT) ? Wm[k * DOUT + n] : 0.0f;
    }
    ws[i] = f2b(v);
}

// async 16B global->LDS copy (HW DMA; dest = base + lane*16)
__device__ __forceinline__ void gll16(const void* g, void* l) {
    __builtin_amdgcn_global_load_lds(
        (const __attribute__((address_space(1))) unsigned int*)g,
        (__attribute__((address_space(3))) unsigned int*)l, 16, 0, 0);
}

// stage one 16KB slab: 4 chunks of 4KB, lane-contiguous (4 vmcnt events)
__device__ __forceinline__ void stage_slab(const unsigned short* __restrict__ src,
                                           unsigned short* dst, int tid) {
    const char* g = (const char*)src + tid * 16;
    char* l = (char*)dst + tid * 16;
    #pragma unroll
    for (int c = 0; c < 4; c++)
        gll16(g + c * 4096, l + c * 4096);
}

// one 32-k slab of MFMAs: A-frag(t) = sb + t*1KB + lane*16B, conflict-free;
// each A-read feeds both r-tiles.
__device__ __forceinline__ void compute_slab(
    f32x4 (&acc)[2][16], const FragU& b0, const FragU& b1,
    const unsigned short* sb, int lane)
{
    __builtin_amdgcn_s_setprio(1);
    #pragma unroll
    for (int t = 0; t < 16; t++) {
        const bf16x8 A = *(const bf16x8*)&sb[(t * 64 + lane) * 8];
        acc[0][t] = __builtin_amdgcn_mfma_f32_16x16x32_bf16(A, b0.v, acc[0][t], 0, 0, 0);
        acc[1][t] = __builtin_amdgcn_mfma_f32_16x16x32_bf16(A, b1.v, acc[1][t], 0, 0, 0);
    }
    __builtin_amdgcn_s_setprio(0);
}

#define SV2(v, a, b) __builtin_shufflevector(v, v, a, b)

// LayerNorm + ReLU + bf16 pack, packed-f32 (f32x2 -> v_pk_*). Bias already
// in acc. B-frags lane-local thanks to phi:
//   u[0..1] <- features 32ks+4q+{0..3}    (t = 2ks)
//   u[2..3] <- features 32ks+16+4q+{0..3} (t = 2ks+1)
__device__ __forceinline__ void build_frags(
    const f32x4 (&acc)[2][16], FragU (&bfo)[2][8],
    const float* __restrict__ gt, const float* __restrict__ bt, int lane)
{
    const int q4 = (lane >> 4) * 4;
    #pragma unroll
    for (int rt = 0; rt < 2; rt++) {
        f32x2 s2 = {0.f, 0.f}, p2 = {0.f, 0.f};
        #pragma unroll
        for (int t = 0; t < 16; t++) {
            const f32x2 a = SV2(acc[rt][t], 0, 1);
            const f32x2 b = SV2(acc[rt][t], 2, 3);
            s2 += a; s2 += b;
            p2 += a * a; p2 += b * b;
        }
        float ss = s2[0] + s2[1];
        float qq = p2[0] + p2[1];
        ss += __shfl_xor(ss, 16); ss += __shfl_xor(ss, 32);
        qq += __shfl_xor(qq, 16); qq += __shfl_xor(qq, 32);
        const float mu = ss * (1.0f / 256.0f);
        const float rs = __builtin_amdgcn_rsqf(
            fmaxf(qq * (1.0f / 256.0f) - mu * mu, 0.0f) + EPSV);
        const float nb = -mu * rs;
        const f32x2 rs2 = {rs, rs}, nb2 = {nb, nb}, z2 = {0.f, 0.f};
        #pragma unroll
        for (int ks = 0; ks < 8; ks++) {
            const f32x4 g0 = *(const f32x4*)&gt[32 * ks + q4];
            const f32x4 e0 = *(const f32x4*)&bt[32 * ks + q4];
            const f32x4 g1 = *(const f32x4*)&gt[32 * ks + 16 + q4];
            const f32x4 e1 = *(const f32x4*)&bt[32 * ks + 16 + q4];
            const f32x2 v00 = SV2(acc[rt][2 * ks], 0, 1);
            const f32x2 v01 = SV2(acc[rt][2 * ks], 2, 3);
            const f32x2 v10 = SV2(acc[rt][2 * ks + 1], 0, 1);
            const f32x2 v11 = SV2(acc[rt][2 * ks + 1], 2, 3);
            const f32x2 w00 = __builtin_elementwise_max(
                (v00 * rs2 + nb2) * SV2(g0, 0, 1) + SV2(e0, 0, 1), z2);
            const f32x2 w01 = __builtin_elementwise_max(
                (v01 * rs2 + nb2) * SV2(g0, 2, 3) + SV2(e0, 2, 3), z2);
            const f32x2 w10 = __builtin_elementwise_max(
                (v10 * rs2 + nb2) * SV2(g1, 0, 1) + SV2(e1, 0, 1), z2);
            const f32x2 w11 = __builtin_elementwise_max(
                (v11 * rs2 + nb2) * SV2(g1, 2, 3) + SV2(e1, 2, 3), z2);
            bfo[rt][ks].u[0] = packbf(w00[0], w00[1]);
            bfo[rt][ks].u[1] = packbf(w01[0], w01[1]);
            bfo[rt][ks].u[2] = packbf(w10[0], w10[1]);
            bfo[rt][ks].u[3] = packbf(w11[0], w11[1]);
        }
    }
}

__device__ __forceinline__ void zero_acc(f32x4 (&acc)[2][16]) {
    #pragma unroll
    for (int rt = 0; rt < 2; rt++)
        #pragma unroll
        for (int t = 0; t < 16; t++)
            acc[rt][t] = (f32x4){0.f, 0.f, 0.f, 0.f};
}

__device__ __forceinline__ void init_acc_bias(f32x4 (&acc)[2][16],
                                              const float* __restrict__ bt, int q) {
    #pragma unroll
    for (int t = 0; t < 16; t++) {
        const f32x4 b = *(const f32x4*)&bt[16 * t + 4 * q];
        acc[0][t] = b;
        acc[1][t] = b;
    }
}

__global__ __launch_bounds__(256, 2) void fused_mlp(
    const float* __restrict__ x,
    const float* __restrict__ g1, const float* __restrict__ be1,
    const float* __restrict__ b2, const float* __restrict__ g2, const float* __restrict__ be2,
    const float* __restrict__ b3, const float* __restrict__ g3, const float* __restrict__ be3,
    const float* __restrict__ bm,
    const unsigned short* __restrict__ ws,
    float* __restrict__ out)
{
    __shared__ unsigned short buf[4][8192];    // 64 KB: quad-buffered 16KB slabs
    __shared__ float gtab[3][256];             // 3 KB gamma
    __shared__ float betab[3][256];            // 3 KB beta
    __shared__ float btab[2][256];             // 2 KB b2,b3
    __shared__ float bmt[16];
    __shared__ float ostage[4][384];           // 6 KB -> ~78 KB total (2 blk/CU)

    const int tid = threadIdx.x;
    const int wv = tid >> 6, lane = tid & 63;
    const int l15 = lane & 15, q = lane >> 4;
    const int wrow0 = blockIdx.x * ROWS_PER_BLOCK + wv * 32;

    const unsigned short* w1f = ws + W1F_OFF;
    const unsigned short* w2f = ws + W2F_OFF;
    const unsigned short* w3f = ws + W3F_OFF;
    const unsigned short* wmf = ws + WMF_OFF;

    // ---- prologue: stage W1 slabs 0,1 (8 loads in flight) ----
    stage_slab(w1f, &buf[0][0], tid);
    stage_slab(w1f + 8192, &buf[1][0], tid);

    // ---- tables -> LDS ----
    {
        const int n = tid;
        gtab[0][n] = g1[n];  betab[0][n] = be1[n];
        gtab[1][n] = g2[n];  betab[1][n] = be2[n];
        gtab[2][n] = g3[n];  betab[2][n] = be3[n];
        btab[0][n] = b2[n];
        btab[1][n] = b3[n];
        if (tid < 16) bmt[tid] = (tid < DOUT) ? bm[tid] : 0.f;
    }
    // ---- x -> layer-1 B-frags (into bf[rt][0..1]), bias = k=48 ones-row ----
    FragU bf[2][8];
    #pragma unroll
    for (int rt = 0; rt < 2; rt++) {
        const float* xr = x + (size_t)(wrow0 + rt * 16 + l15) * DIN;
        const float4 f0 = *(const float4*)(xr + q * 8);
        const float4 f1 = *(const float4*)(xr + q * 8 + 4);
        bf[rt][0].u[0] = packbf(f0.x, f0.y); bf[rt][0].u[1] = packbf(f0.z, f0.w);
        bf[rt][0].u[2] = packbf(f1.x, f1.y); bf[rt][0].u[3] = packbf(f1.z, f1.w);
        if (q < 2) {
            const float4 f2 = *(const float4*)(xr + 32 + q * 8);
            const float4 f3 = *(const float4*)(xr + 36 + q * 8);
            bf[rt][1].u[0] = packbf(f2.x, f2.y); bf[rt][1].u[1] = packbf(f2.z, f2.w);
            bf[rt][1].u[2] = packbf(f3.x, f3.y); bf[rt][1].u[3] = packbf(f3.z, f3.w);
        } else if (q == 2) {
            bf[rt][1].u[0] = 0x00003F80u;  // k=48 -> 1.0 (bias row)
            bf[rt][1].u[1] = 0u; bf[rt][1].u[2] = 0u; bf[rt][1].u[3] = 0u;
        } else {
            bf[rt][1].u[0] = 0u; bf[rt][1].u[1] = 0u;
            bf[rt][1].u[2] = 0u; bf[rt][1].u[3] = 0u;
        }
    }
    // one-time fence: table ds_writes visible before first raw barrier
    asm volatile("s_waitcnt lgkmcnt(0)" ::: "memory");

    f32x4 acc[2][16];

    // ================= pipelined 18-slab main loop =================
    // step sigma: stage(sigma+2) -> vmcnt(8) -> s_barrier -> compute(sigma)
    // quad-buffer ring: writer sigma+2 vs readers sigma-2 (distance 4, safe).

    // ---- layer 1: sigma = 0,1 ----
    zero_acc(acc);                       // layer-1 bias is the k=48 ones-row
    #pragma unroll
    for (int s = 0; s < 2; s++) {
        stage_slab(w2f + s * 8192, &buf[(s + 2) & 3][0], tid);
        WAITV(8);
        __builtin_amdgcn_s_barrier();
        __builtin_amdgcn_sched_barrier(0);
        compute_slab(acc, bf[0][s], bf[1][s], &buf[s][0], lane);
    }
    build_frags(acc, bf, &gtab[0][0], &betab[0][0], lane);

    // ---- layer 2: sigma = 2..9 ----
    init_acc_bias(acc, &btab[0][0], q);  // b2
    #pragma unroll
    for (int s = 0; s < 8; s++) {
        const unsigned short* nsrc = (s < 6) ? (w2f + (s + 2) * 8192)
                                             : (w3f + (s - 6) * 8192);
        stage_slab(nsrc, &buf[(s + 4) & 3][0], tid);
        WAITV(8);
        __builtin_amdgcn_s_barrier();
        __builtin_amdgcn_sched_barrier(0);
        compute_slab(acc, bf[0][s], bf[1][s], &buf[(s + 2) & 3][0], lane);
    }
    build_frags(acc, bf, &gtab[1][0], &betab[1][0], lane);

    // ---- layer 3: sigma = 10..17 ----
    init_acc_bias(acc, &btab[1][0], q);  // b3
    #pragma unroll
    for (int s = 0; s < 8; s++) {
        if (s < 6) stage_slab(w3f + (s + 2) * 8192, &buf[(s + 12) & 3][0], tid);
        if (s < 6)      { WAITV(8); }
        else if (s == 6){ WAITV(4); }
        else            { WAITV(0); }
        __builtin_amdgcn_s_barrier();
        __builtin_amdgcn_sched_barrier(0);
        compute_slab(acc, bf[0][s], bf[1][s], &buf[(s + 10) & 3][0], lane);
    }
    build_frags(acc, bf, &gtab[2][0], &betab[2][0], lane);

    // ---- final layer: Wm frag-major (phi k-order) from global (L2-resident) ----
    f32x4 facc[2];
    {
        const f32x4 bm4 = *(const f32x4*)&bmt[4 * q];
        facc[0] = bm4;
        facc[1] = bm4;
    }
    #pragma unroll
    for (int ks = 0; ks < 8; ks++) {
        const bf16x8 A = *(const bf16x8*)&wmf[(ks * 64 + lane) * 8];
        facc[0] = __builtin_amdgcn_mfma_f32_16x16x32_bf16(A, bf[0][ks].v, facc[0], 0, 0, 0);
        facc[1] = __builtin_amdgcn_mfma_f32_16x16x32_bf16(A, bf[1][ks].v, facc[1], 0, 0, 0);
    }
    // tanh -> wave-private LDS staging (row = rt*16+l15, cols 4q..4q+3 for q<3)
    if (q < 3) {
        #pragma unroll
        for (int rt = 0; rt < 2; rt++) {
            float4 o;
            o.x = fast_tanh(facc[rt][0]);
            o.y = fast_tanh(facc[rt][1]);
            o.z = fast_tanh(facc[rt][2]);
            o.w = fast_tanh(facc[rt][3]);
            *(float4*)&ostage[wv][(rt * 16 + l15) * 12 + q * 4] = o;
        }
    }
    // coalesced store: 32 rows x 12 f32 = 96 float4 per wave (same-wave LDS,
    // compiler handles lgkm ordering; no block barrier needed)
    float4* og = (float4*)(out + (size_t)wrow0 * DOUT);
    const float4* ov = (const float4*)&ostage[wv][0];
    og[lane] = ov[lane];
    if (lane < 32) og[64 + lane] = ov[64 + lane];
}

extern "C" void kernel_launch(void* const* d_in, const int* in_sizes, int n_in,
                              void* d_out, int out_size, void* d_ws, size_t ws_size,
                              hipStream_t stream)
{
    const float* x   = (const float*)d_in[0];
    const float* W1  = (const float*)d_in[1];
    const float* b1  = (const float*)d_in[2];
    const float* g1  = (const float*)d_in[3];
    const float* be1 = (const float*)d_in[4];
    const float* W2  = (const float*)d_in[5];
    const float* b2  = (const float*)d_in[6];
    const float* g2  = (const float*)d_in[7];
    const float* be2 = (const float*)d_in[8];
    const float* W3  = (const float*)d_in[9];
    const float* b3  = (const float*)d_in[10];
    const float* g3  = (const float*)d_in[11];
    const float* be3 = (const float*)d_in[12];
    const float* Wm  = (const float*)d_in[13];
    const float* bm  = (const float*)d_in[14];
    unsigned short* ws = (unsigned short*)d_ws;
    float* out = (float*)d_out;

    conv_w_kernel<<<(WS_ELEMS + 255) / 256, 256, 0, stream>>>(W1, b1, W2, W3, Wm, ws);
    fused_mlp<<<NBLK, 256, 0, stream>>>(x, g1, be1, b2, g2, be2,
                                        b3, g3, be3, bm, ws, out);
}